// Round 1
// baseline (525.911 us; speedup 1.0000x reference)
//
#include <hip/hip_runtime.h>
#include <hip/hip_bf16.h>

typedef __bf16 bf16_t;
typedef __bf16 bf16x4_t __attribute__((ext_vector_type(4)));
typedef __bf16 bf16x8_t __attribute__((ext_vector_type(8)));
typedef float  f32x4_t  __attribute__((ext_vector_type(4)));

#define B_   8
#define LQ_  512
#define LKV_ 512
#define D_   1024
#define H_   16
#define DH_  64
#define FF_  4096

__device__ __forceinline__ f32x4_t mfma16(bf16x8_t a, bf16x8_t b, f32x4_t c) {
    return __builtin_amdgcn_mfma_f32_16x16x32_bf16(a, b, c, 0, 0, 0);
}

__device__ __forceinline__ void gload_lds16(const bf16_t* g, bf16_t* l) {
    __builtin_amdgcn_global_load_lds(
        (const __attribute__((address_space(1))) void*)g,
        (__attribute__((address_space(3))) void*)l, 16, 0, 0);
}

// ---------------------------------------------------------------------------
// f32 -> bf16 convert (vectorized)
// ---------------------------------------------------------------------------
__global__ __launch_bounds__(256)
void cvt_bf16_kernel(const float* __restrict__ in, bf16_t* __restrict__ out, int n4) {
    const int i = blockIdx.x * 256 + threadIdx.x;
    if (i >= n4) return;
    const float4 v = ((const float4*)in)[i];
    bf16x4_t o;
    o[0] = (bf16_t)v.x; o[1] = (bf16_t)v.y; o[2] = (bf16_t)v.z; o[3] = (bf16_t)v.w;
    ((bf16x4_t*)out)[i] = o;
}

// ---------------------------------------------------------------------------
// AttentionBiasMLP: bias[b,h,q,k] = Wc2 @ gelu(Wc1 @ log(amap[b,:,q+1,k+1]+eps) + bc1) + bc2
// one thread per (b,q,k) position
// ---------------------------------------------------------------------------
__global__ __launch_bounds__(256)
void bias_mlp_kernel(const float* __restrict__ amap,
                     const float* __restrict__ Wc1, const float* __restrict__ bc1,
                     const float* __restrict__ Wc2, const float* __restrict__ bc2,
                     bf16_t* __restrict__ biasb) {
    __shared__ float w1[512], w2[512], b1s[32], b2s[16];
    const int t = threadIdx.x;
    for (int i = t; i < 512; i += 256) { w1[i] = Wc1[i]; w2[i] = Wc2[i]; }
    if (t < 32) b1s[t] = bc1[t];
    if (t < 16) b2s[t] = bc2[t];
    __syncthreads();

    const int gid = blockIdx.x * 256 + t;             // over B*LQ*LKV = 2^21
    const int k = gid & 511, q = (gid >> 9) & 511, b = gid >> 18;
    const float* base = amap + (size_t)b * 16 * 263169 + (size_t)(q + 1) * 513 + (k + 1);

    float in[16];
#pragma unroll
    for (int c = 0; c < 16; c++) in[c] = __logf(base[(size_t)c * 263169] + 1e-6f);

    float acc[16];
#pragma unroll
    for (int o = 0; o < 16; o++) acc[o] = b2s[o];
    for (int j = 0; j < 32; j++) {
        float hj = b1s[j];
#pragma unroll
        for (int c = 0; c < 16; c++) hj += w1[j * 16 + c] * in[c];
        hj = 0.5f * hj * (1.f + erff(hj * 0.70710678118654752f));   // exact GELU
#pragma unroll
        for (int o = 0; o < 16; o++) acc[o] += w2[o * 32 + j] * hj;
    }
    const size_t ob = ((size_t)(b * 16) * 512 + q) * 512 + k;
#pragma unroll
    for (int o = 0; o < 16; o++) biasb[ob + (size_t)o * 262144] = (bf16_t)acc[o];
}

// ---------------------------------------------------------------------------
// bf16 GEMM: C[M,N] = A[M,K] @ W[N,K]^T + bias   (m97 structure: 128x128 tile,
// BK=32, global_load_lds staging, 4 waves 2x2, 16x16x32 MFMA)
// EPI: 0 = f32 out, 1 = bf16 out, 2 = relu -> bf16 out
// ---------------------------------------------------------------------------
template <int EPI>
__global__ __launch_bounds__(256)
void gemm_bt(const bf16_t* __restrict__ A, const bf16_t* __restrict__ Bw,
             const float* __restrict__ bias, float* __restrict__ Cf,
             bf16_t* __restrict__ Cb, int M, int N, int K) {
    __shared__ __align__(16) bf16_t As[128 * 32];
    __shared__ __align__(16) bf16_t Bs[128 * 32];
    const int t = threadIdx.x, lane = t & 63, w = t >> 6;
    const int wr = w >> 1, wc = w & 1;
    const int tn_cnt = N >> 7;
    const int tm = blockIdx.x / tn_cnt, tn = blockIdx.x % tn_cnt;
    const int l15 = lane & 15, lg = lane >> 4;

    f32x4_t acc[4][4];
#pragma unroll
    for (int i = 0; i < 4; i++)
#pragma unroll
        for (int j = 0; j < 4; j++) acc[i][j] = f32x4_t{0.f, 0.f, 0.f, 0.f};

    const int nk = K >> 5;
    for (int kt = 0; kt < nk; ++kt) {
#pragma unroll
        for (int i = 0; i < 2; i++) {
            const int c = i * 256 + w * 64 + lane;
            const int c0 = i * 256 + w * 64;
            const int row = c >> 2, kg = c & 3;
            gload_lds16(A + (size_t)(tm * 128 + row) * K + kt * 32 + kg * 8, &As[c0 * 8]);
        }
#pragma unroll
        for (int i = 0; i < 2; i++) {
            const int c = i * 256 + w * 64 + lane;
            const int c0 = i * 256 + w * 64;
            const int row = c >> 2, kg = c & 3;
            gload_lds16(Bw + (size_t)(tn * 128 + row) * K + kt * 32 + kg * 8, &Bs[c0 * 8]);
        }
        __syncthreads();

        bf16x8_t af[4], bfv[4];
#pragma unroll
        for (int mt = 0; mt < 4; mt++)
            af[mt] = *(const bf16x8_t*)&As[(wr * 64 + mt * 16 + l15) * 32 + lg * 8];
#pragma unroll
        for (int nt = 0; nt < 4; nt++)
            bfv[nt] = *(const bf16x8_t*)&Bs[(wc * 64 + nt * 16 + l15) * 32 + lg * 8];
#pragma unroll
        for (int mt = 0; mt < 4; mt++)
#pragma unroll
            for (int nt = 0; nt < 4; nt++)
                acc[mt][nt] = mfma16(af[mt], bfv[nt], acc[mt][nt]);
        __syncthreads();
    }

#pragma unroll
    for (int nt = 0; nt < 4; nt++) {
        const int col = tn * 128 + wc * 64 + nt * 16 + l15;
        const float bv = bias[col];
#pragma unroll
        for (int mt = 0; mt < 4; mt++) {
#pragma unroll
            for (int r = 0; r < 4; r++) {
                const int row = tm * 128 + wr * 64 + mt * 16 + lg * 4 + r;
                float v = acc[mt][nt][r] + bv;
                if (EPI == 2) v = fmaxf(v, 0.f);
                if (EPI == 0) Cf[(size_t)row * N + col] = v;
                else          Cb[(size_t)row * N + col] = (bf16_t)v;
            }
        }
    }
}

// ---------------------------------------------------------------------------
// Flash attention with additive bias.  One block = (b, h, 64-row q-tile),
// 4 waves; wave w owns q rows [16w,16w+16).  All LDS tiles [64][64] bf16 with
// XOR swizzle (byte ^= (row&7)<<4 on 16B chunks) to kill bank conflicts.
// ---------------------------------------------------------------------------
__global__ __launch_bounds__(256)
void attn_kernel(const bf16_t* __restrict__ Qp, const bf16_t* __restrict__ Kp,
                 const bf16_t* __restrict__ Vp, const bf16_t* __restrict__ biasb,
                 bf16_t* __restrict__ ctx) {
    __shared__ __align__(16) bf16_t Qs[64 * 64];
    __shared__ __align__(16) bf16_t Ks[64 * 64];
    __shared__ __align__(16) bf16_t Vts[64 * 64];   // V transposed: Vts[d][k]
    __shared__ __align__(16) bf16_t Ps[64 * 64];

    const int bid = blockIdx.x;
    const int qt = bid & 7, h = (bid >> 3) & 15, b = bid >> 7;
    const int t = threadIdx.x, lane = t & 63, w = t >> 6;
    const int l15 = lane & 15, lg = lane >> 4;

    // stage Q tile (swizzled)
#pragma unroll
    for (int i = 0; i < 2; i++) {
        const int c = t + i * 256;
        const int row = c >> 3, cg = c & 7;
        const uint4 v = *(const uint4*)&Qp[(((size_t)(b * LQ_ + qt * 64 + row)) * H_ + h) * DH_ + cg * 8];
        *(uint4*)((char*)Qs + row * 128 + ((cg ^ (row & 7)) << 4)) = v;
    }

    f32x4_t oacc[4];
#pragma unroll
    for (int i = 0; i < 4; i++) oacc[i] = f32x4_t{0.f, 0.f, 0.f, 0.f};
    float mrow[4] = {-1e30f, -1e30f, -1e30f, -1e30f};
    float lrow[4] = {0.f, 0.f, 0.f, 0.f};

    const bf16_t* bias_base = biasb + ((size_t)(b * H_ + h) * LQ_ + qt * 64 + w * 16) * LKV_;

    for (int kt = 0; kt < 8; ++kt) {
        __syncthreads();   // previous iteration done with Ks/Vts
#pragma unroll
        for (int i = 0; i < 2; i++) {
            const int c = t + i * 256;
            const int row = c >> 3, cg = c & 7;
            const uint4 v = *(const uint4*)&Kp[(((size_t)(b * LKV_ + kt * 64 + row)) * H_ + h) * DH_ + cg * 8];
            *(uint4*)((char*)Ks + row * 128 + ((cg ^ (row & 7)) << 4)) = v;
        }
#pragma unroll
        for (int i = 0; i < 2; i++) {
            const int c = t + i * 256;
            const int k = c >> 3, dg = c & 7;
            const bf16x8_t vv = *(const bf16x8_t*)&Vp[(((size_t)(b * LKV_ + kt * 64 + k)) * H_ + h) * DH_ + dg * 8];
#pragma unroll
            for (int j = 0; j < 8; j++) {
                const int d = dg * 8 + j;
                *(bf16_t*)((char*)Vts + d * 128 + ((((k * 2) >> 4) ^ (d & 7)) << 4) + ((k * 2) & 15)) = vv[j];
            }
        }
        __syncthreads();

        // S = Q K^T  (A = Q rows of this wave, B = K^T from Ks rows)
        f32x4_t sacc[4];
#pragma unroll
        for (int i = 0; i < 4; i++) sacc[i] = f32x4_t{0.f, 0.f, 0.f, 0.f};
        bf16x8_t aq[2];
        {
            const int rowq = w * 16 + l15;
#pragma unroll
            for (int kc = 0; kc < 2; kc++)
                aq[kc] = *(const bf16x8_t*)((const char*)Qs + rowq * 128 + (((kc * 4 + lg) ^ (rowq & 7)) << 4));
        }
#pragma unroll
        for (int nt = 0; nt < 4; nt++) {
            const int rowk = nt * 16 + l15;
#pragma unroll
            for (int kc = 0; kc < 2; kc++) {
                const bf16x8_t bk = *(const bf16x8_t*)((const char*)Ks + rowk * 128 + (((kc * 4 + lg) ^ (rowk & 7)) << 4));
                sacc[nt] = mfma16(aq[kc], bk, sacc[nt]);
            }
        }

        // bias add + online softmax.  D-layout: row = 4*lg + r, col = 16*nt + l15
        const bf16_t* bb = bias_base + kt * 64;
        float esc[4];
#pragma unroll
        for (int r = 0; r < 4; r++) {
            const int qr = lg * 4 + r;
            float mx = -1e30f;
#pragma unroll
            for (int nt = 0; nt < 4; nt++) {
                const float bvv = (float)bb[(size_t)qr * LKV_ + nt * 16 + l15];
                const float v = sacc[nt][r] * 0.125f + bvv;
                sacc[nt][r] = v;
                mx = fmaxf(mx, v);
            }
#pragma unroll
            for (int msk = 8; msk >= 1; msk >>= 1) mx = fmaxf(mx, __shfl_xor(mx, msk));
            const float mnew = fmaxf(mrow[r], mx);
            esc[r] = __expf(mrow[r] - mnew);
            mrow[r] = mnew;
            float rs = 0.f;
#pragma unroll
            for (int nt = 0; nt < 4; nt++) {
                const float p = __expf(sacc[nt][r] - mnew);
                sacc[nt][r] = p;
                rs += p;
            }
#pragma unroll
            for (int msk = 8; msk >= 1; msk >>= 1) rs += __shfl_xor(rs, msk);
            lrow[r] = lrow[r] * esc[r] + rs;
        }

        // write P (bf16) into own wave strip of Ps
#pragma unroll
        for (int r = 0; r < 4; r++) {
            const int prow = w * 16 + lg * 4 + r;
#pragma unroll
            for (int nt = 0; nt < 4; nt++) {
                const int pc2 = (nt * 16 + l15) * 2;
                *(bf16_t*)((char*)Ps + prow * 128 + (((pc2 >> 4) ^ (prow & 7)) << 4) + (pc2 & 15)) =
                    (bf16_t)sacc[nt][r];
            }
        }
        asm volatile("s_waitcnt lgkmcnt(0)" ::: "memory");
        __builtin_amdgcn_sched_barrier(0);

        // rescale O then accumulate P @ V
#pragma unroll
        for (int dt = 0; dt < 4; dt++)
#pragma unroll
            for (int r = 0; r < 4; r++) oacc[dt][r] *= esc[r];

        bf16x8_t pa[2];
        {
            const int rowp = w * 16 + l15;
#pragma unroll
            for (int kc = 0; kc < 2; kc++)
                pa[kc] = *(const bf16x8_t*)((const char*)Ps + rowp * 128 + (((kc * 4 + lg) ^ (rowp & 7)) << 4));
        }
#pragma unroll
        for (int dt = 0; dt < 4; dt++) {
            const int rowv = dt * 16 + l15;
#pragma unroll
            for (int kc = 0; kc < 2; kc++) {
                const bf16x8_t bv = *(const bf16x8_t*)((const char*)Vts + rowv * 128 + (((kc * 4 + lg) ^ (rowv & 7)) << 4));
                oacc[dt] = mfma16(pa[kc], bv, oacc[dt]);
            }
        }
    }

#pragma unroll
    for (int dt = 0; dt < 4; dt++) {
#pragma unroll
        for (int r = 0; r < 4; r++) {
            const float v = oacc[dt][r] / lrow[r];
            const int q = qt * 64 + w * 16 + lg * 4 + r;
            const int d = dt * 16 + l15;
            ctx[(((size_t)(b * LQ_ + q)) * H_ + h) * DH_ + d] = (bf16_t)v;
        }
    }
}

// ---------------------------------------------------------------------------
// out = LayerNorm(X + Y) * g + b ; optional bf16 copy.  One block per row.
// ---------------------------------------------------------------------------
__global__ __launch_bounds__(256)
void add_ln_kernel(const float* __restrict__ X, const float* __restrict__ Y,
                   const float* __restrict__ g, const float* __restrict__ be,
                   float* __restrict__ of, bf16_t* __restrict__ ob) {
    const int row = blockIdx.x, t = threadIdx.x;
    const float4 xv = ((const float4*)(X + (size_t)row * 1024))[t];
    const float4 yv = ((const float4*)(Y + (size_t)row * 1024))[t];
    float v[4] = {xv.x + yv.x, xv.y + yv.y, xv.z + yv.z, xv.w + yv.w};
    float s = v[0] + v[1] + v[2] + v[3];
    float s2 = v[0] * v[0] + v[1] * v[1] + v[2] * v[2] + v[3] * v[3];
#pragma unroll
    for (int m = 32; m >= 1; m >>= 1) { s += __shfl_xor(s, m); s2 += __shfl_xor(s2, m); }
    __shared__ float red[8];
    const int w = t >> 6, lane = t & 63;
    if (lane == 0) { red[w] = s; red[4 + w] = s2; }
    __syncthreads();
    s = red[0] + red[1] + red[2] + red[3];
    s2 = red[4] + red[5] + red[6] + red[7];
    const float mu = s * (1.f / 1024.f);
    const float var = s2 * (1.f / 1024.f) - mu * mu;
    const float rstd = rsqrtf(var + 1e-6f);
    const float4 gv = ((const float4*)g)[t];
    const float4 bv = ((const float4*)be)[t];
    float o[4];
    o[0] = (v[0] - mu) * rstd * gv.x + bv.x;
    o[1] = (v[1] - mu) * rstd * gv.y + bv.y;
    o[2] = (v[2] - mu) * rstd * gv.z + bv.z;
    o[3] = (v[3] - mu) * rstd * gv.w + bv.w;
    ((float4*)(of + (size_t)row * 1024))[t] = make_float4(o[0], o[1], o[2], o[3]);
    if (ob) {
        bf16x4_t qo;
        qo[0] = (bf16_t)o[0]; qo[1] = (bf16_t)o[1]; qo[2] = (bf16_t)o[2]; qo[3] = (bf16_t)o[3];
        ((bf16x4_t*)(ob + (size_t)row * 1024))[t] = qo;
    }
}

// ---------------------------------------------------------------------------
extern "C" void kernel_launch(void* const* d_in, const int* in_sizes, int n_in,
                              void* d_out, int out_size, void* d_ws, size_t ws_size,
                              hipStream_t stream) {
    (void)in_sizes; (void)n_in; (void)out_size; (void)ws_size;
    const float* q    = (const float*)d_in[0];
    const float* kv   = (const float*)d_in[1];
    const float* amap = (const float*)d_in[2];
    const float* Wq = (const float*)d_in[3];  const float* bQ = (const float*)d_in[4];
    const float* Wk = (const float*)d_in[5];  const float* bK = (const float*)d_in[6];
    const float* Wv = (const float*)d_in[7];  const float* bV = (const float*)d_in[8];
    const float* Wm = (const float*)d_in[9];  const float* bM = (const float*)d_in[10];
    const float* Wc1 = (const float*)d_in[11]; const float* bc1 = (const float*)d_in[12];
    const float* Wc2 = (const float*)d_in[13]; const float* bc2 = (const float*)d_in[14];
    const float* Wf1 = (const float*)d_in[15]; const float* bf1 = (const float*)d_in[16];
    const float* Wf2 = (const float*)d_in[17]; const float* bf2 = (const float*)d_in[18];
    const float* g1 = (const float*)d_in[19]; const float* b1 = (const float*)d_in[20];
    const float* g2 = (const float*)d_in[21]; const float* b2 = (const float*)d_in[22];

    char* w = (char*)d_ws;
    bf16_t* biasb = (bf16_t*)(w);                  // 67,108,864 B
    bf16_t* Qp   = (bf16_t*)(w + 67108864);        // 8,388,608 B
    bf16_t* Kp   = (bf16_t*)(w + 75497472);
    bf16_t* Vp   = (bf16_t*)(w + 83886080);
    bf16_t* qb   = (bf16_t*)(w + 92274688);
    bf16_t* kvb  = (bf16_t*)(w + 100663296);
    bf16_t* Wqb  = (bf16_t*)(w + 109051904);       // 2,097,152 B each
    bf16_t* Wkb  = (bf16_t*)(w + 111149056);
    bf16_t* Wvb  = (bf16_t*)(w + 113246208);
    bf16_t* Wmb  = (bf16_t*)(w + 115343360);
    bf16_t* Wf1b = (bf16_t*)(w + 117440512);       // 8,388,608
    bf16_t* Wf2b = (bf16_t*)(w + 125829120);
    float*  atted = (float*)(w + 134217728);       // 16,777,216  (total 150,994,944 B)
    // dead-buffer reuse (all ordering-safe on one stream):
    bf16_t* ctx = qb;                 // qb dead after Q projection
    float*  xf  = (float*)Qp;         // Qp/Kp dead after attention
    bf16_t* xb  = Vp;                 // Vp dead after attention
    bf16_t* hb  = (bf16_t*)(w);       // bias dead after attention (33.5 MB)
    float*  ffn = (float*)(w + 33554432);          // 16.8 MB, still inside old bias region

    dim3 blk(256);
    cvt_bf16_kernel<<<4096, blk, 0, stream>>>(q,   qb,   1048576);
    cvt_bf16_kernel<<<4096, blk, 0, stream>>>(kv,  kvb,  1048576);
    cvt_bf16_kernel<<<1024, blk, 0, stream>>>(Wq,  Wqb,  262144);
    cvt_bf16_kernel<<<1024, blk, 0, stream>>>(Wk,  Wkb,  262144);
    cvt_bf16_kernel<<<1024, blk, 0, stream>>>(Wv,  Wvb,  262144);
    cvt_bf16_kernel<<<1024, blk, 0, stream>>>(Wm,  Wmb,  262144);
    cvt_bf16_kernel<<<4096, blk, 0, stream>>>(Wf1, Wf1b, 1048576);
    cvt_bf16_kernel<<<4096, blk, 0, stream>>>(Wf2, Wf2b, 1048576);

    bias_mlp_kernel<<<8192, blk, 0, stream>>>(amap, Wc1, bc1, Wc2, bc2, biasb);

    gemm_bt<1><<<256, blk, 0, stream>>>(qb,  Wqb, bQ, nullptr, Qp, 4096, 1024, 1024);
    gemm_bt<1><<<256, blk, 0, stream>>>(kvb, Wkb, bK, nullptr, Kp, 4096, 1024, 1024);
    gemm_bt<1><<<256, blk, 0, stream>>>(kvb, Wvb, bV, nullptr, Vp, 4096, 1024, 1024);

    attn_kernel<<<1024, blk, 0, stream>>>(Qp, Kp, Vp, biasb, ctx);

    gemm_bt<0><<<256, blk, 0, stream>>>(ctx, Wmb, bM, atted, nullptr, 4096, 1024, 1024);
    add_ln_kernel<<<4096, blk, 0, stream>>>(q, atted, g1, b1, xf, xb);

    gemm_bt<2><<<1024, blk, 0, stream>>>(xb, Wf1b, bf1, nullptr, hb, 4096, 4096, 1024);
    gemm_bt<0><<<256, blk, 0, stream>>>(hb, Wf2b, bf2, ffn, nullptr, 4096, 1024, 4096);
    add_ln_kernel<<<4096, blk, 0, stream>>>(xf, ffn, g2, b2, (float*)d_out, nullptr);
}

// Round 3
// 401.098 us; speedup vs baseline: 1.3112x; 1.3112x over previous
//
#include <hip/hip_runtime.h>
#include <hip/hip_bf16.h>

typedef __bf16 bf16_t;
typedef __bf16 bf16x4_t __attribute__((ext_vector_type(4)));
typedef __bf16 bf16x8_t __attribute__((ext_vector_type(8)));
typedef float  f32x4_t  __attribute__((ext_vector_type(4)));

#define B_   8
#define LQ_  512
#define LKV_ 512
#define D_   1024
#define H_   16
#define DH_  64
#define FF_  4096

__device__ __forceinline__ f32x4_t mfma16(bf16x8_t a, bf16x8_t b, f32x4_t c) {
    return __builtin_amdgcn_mfma_f32_16x16x32_bf16(a, b, c, 0, 0, 0);
}

__device__ __forceinline__ void gload_lds16(const bf16_t* g, bf16_t* l) {
    __builtin_amdgcn_global_load_lds(
        (const __attribute__((address_space(1))) void*)g,
        (__attribute__((address_space(3))) void*)l, 16, 0, 0);
}

// ---------------------------------------------------------------------------
// f32 -> bf16 convert (vectorized)
// ---------------------------------------------------------------------------
__global__ __launch_bounds__(256)
void cvt_bf16_kernel(const float* __restrict__ in, bf16_t* __restrict__ out, int n4) {
    const int i = blockIdx.x * 256 + threadIdx.x;
    if (i >= n4) return;
    const float4 v = ((const float4*)in)[i];
    bf16x4_t o;
    o[0] = (bf16_t)v.x; o[1] = (bf16_t)v.y; o[2] = (bf16_t)v.z; o[3] = (bf16_t)v.w;
    ((bf16x4_t*)out)[i] = o;
}

__global__ __launch_bounds__(256)
void pack3_kernel(const float* __restrict__ a, const float* __restrict__ b,
                  const float* __restrict__ c, float* __restrict__ o) {
    const int i = blockIdx.x * 256 + threadIdx.x;   // grid 4 -> i < 1024
    o[i] = a[i]; o[1024 + i] = b[i]; o[2048 + i] = c[i];
}

// ---------------------------------------------------------------------------
// AttentionBiasMLP via MFMA.  One wave handles 64 consecutive positions
// (same b,q; k = k0..k0+63).  Wave-private LDS; no block barriers.
// Layer1: [64,16(pad32)] @ W1^T[16,32] -> gelu -> Layer2: [64,32] @ W2^T[32,16]
// NOTE: lanes with lg>=2 have a zero B-fragment; their A-fragment LDS offset is
// clamped to (lg&1)*16 so they read VALID bytes (0 x NaN-garbage = NaN bug!).
// ---------------------------------------------------------------------------
__global__ __launch_bounds__(256)
void bias_mlp_mfma(const float* __restrict__ amap,
                   const float* __restrict__ Wc1, const float* __restrict__ bc1,
                   const float* __restrict__ Wc2, const float* __restrict__ bc2,
                   bf16_t* __restrict__ biasb) {
    __shared__ __align__(16) char lds[4][8192];  // per wave: Xs [0,3072) rows 48B; Hs [3072,8192) rows 80B
    const int t = threadIdx.x, lane = t & 63, w = t >> 6;
    const int l15 = lane & 15, lg = lane >> 4;
    char* Xs = lds[w];
    char* Hs = lds[w] + 3072;

    // --- weight fragments (registers, uniform-ish loads, once) ---
    bf16x8_t b1f[2], b2f;
    f32x4_t bc1v[2];
#pragma unroll
    for (int ot = 0; ot < 2; ot++) {
        bf16x8_t v;
#pragma unroll
        for (int i = 0; i < 8; i++) {
            const int kk = (lg * 8 + i) & 15;                       // in-bounds always
            const float wv = Wc1[(ot * 16 + l15) * 16 + kk];
            v[i] = (lg < 2) ? (bf16_t)wv : (bf16_t)0.f;             // zero-pad K 16->32
        }
        b1f[ot] = v;
        const float bb = bc1[ot * 16 + l15];
        bc1v[ot] = f32x4_t{bb, bb, bb, bb};
    }
    {
        bf16x8_t v;
#pragma unroll
        for (int i = 0; i < 8; i++) v[i] = (bf16_t)Wc2[l15 * 32 + lg * 8 + i];
        b2f = v;
    }
    const float bc2s = bc2[l15];
    const f32x4_t cinit2 = f32x4_t{bc2s, bc2s, bc2s, bc2s};

    // --- positions ---
    const int posb = (blockIdx.x * 4 + w) * 64;
    const int b  = posb >> 18;
    const int q  = (posb >> 9) & 511;
    const int k0 = posb & 511;

    // --- load 16 channels, log, stage to LDS (row = lane, 16 bf16, stride 48B) ---
    const float* src = amap + (size_t)(b * 16) * 263169 + (size_t)(q + 1) * 513 + (k0 + 1 + lane);
    bf16_t xr[16];
#pragma unroll
    for (int c = 0; c < 16; c++) {
        const float v = src[(size_t)c * 263169];
        xr[c] = (bf16_t)__logf(v + 1e-6f);
    }
    *(bf16x8_t*)(Xs + lane * 48)      = *(bf16x8_t*)&xr[0];
    *(bf16x8_t*)(Xs + lane * 48 + 16) = *(bf16x8_t*)&xr[8];

    // --- layer 1 MFMA: A-frag row=l15 (pos); lg>=2 lanes re-read valid bytes, B=0 there ---
    const int lgm16 = (lg & 1) * 16;
    f32x4_t h1[4][2];
#pragma unroll
    for (int p = 0; p < 4; p++) {
        const bf16x8_t a1 = *(const bf16x8_t*)(Xs + (p * 16 + l15) * 48 + lgm16);
#pragma unroll
        for (int ot = 0; ot < 2; ot++)
            h1[p][ot] = mfma16(a1, b1f[ot], bc1v[ot]);
    }

    // --- exact GELU (A&S 7.1.26 erf, |eps|<=1.5e-7), write H to LDS [64][40bf16] ---
#pragma unroll
    for (int p = 0; p < 4; p++)
#pragma unroll
        for (int ot = 0; ot < 2; ot++)
#pragma unroll
            for (int r = 0; r < 4; r++) {
                const float h = h1[p][ot][r];
                const float z = h * 0.70710678118654752f;
                const float az = fabsf(z);
                const float t1 = 1.f / (1.f + 0.3275911f * az);
                const float poly = ((((1.061405429f * t1 - 1.453152027f) * t1 + 1.421413741f) * t1
                                     - 0.284496736f) * t1 + 0.254829592f) * t1;
                const float e = __expf(-z * z);
                const float erfa = 1.f - poly * e;
                const float erfv = (z >= 0.f) ? erfa : -erfa;
                const float g = 0.5f * h * (1.f + erfv);
                *(bf16_t*)(Hs + (p * 16 + lg * 4 + r) * 80 + (ot * 16 + l15) * 2) = (bf16_t)g;
            }

    // --- layer 2 MFMA + direct bf16x4 store (C rows are 4 consecutive k) ---
    const size_t obase = ((size_t)(b * 16 + l15) * 512 + q) * 512 + k0;
#pragma unroll
    for (int p = 0; p < 4; p++) {
        const bf16x8_t a2 = *(const bf16x8_t*)(Hs + (p * 16 + l15) * 80 + lg * 16);
        const f32x4_t o2 = mfma16(a2, b2f, cinit2);
        bf16x4_t ov;
#pragma unroll
        for (int r = 0; r < 4; r++) ov[r] = (bf16_t)o2[r];
        *(bf16x4_t*)&biasb[obase + p * 16 + lg * 4] = ov;
    }
}

// ---------------------------------------------------------------------------
// bf16 GEMM: C[M,N] = A[M,K] @ W[N,K]^T + bias   (m97 structure: 128x128 tile,
// BK=32, global_load_lds staging, 4 waves 2x2, 16x16x32 MFMA)
// EPI: 0 = f32 out, 1 = bf16 out, 2 = relu -> bf16 out, 3 = QKV fused bf16 out
// SPLIT: blockIdx.y selects K-half; f32 partials at Cf + ks*M*N; bias on ks==0
// ---------------------------------------------------------------------------
template <int EPI, bool SPLIT>
__global__ __launch_bounds__(256)
void gemm_bt(const bf16_t* __restrict__ A, const bf16_t* __restrict__ A2,
             const bf16_t* __restrict__ Bw,
             const float* __restrict__ bias, float* __restrict__ Cf,
             bf16_t* __restrict__ Cb, int M, int N, int Klen, int lda) {
    __shared__ __align__(16) bf16_t As[128 * 32];
    __shared__ __align__(16) bf16_t Bs[128 * 32];
    const int t = threadIdx.x, lane = t & 63, w = t >> 6;
    const int wr = w >> 1, wc = w & 1;
    const int tn_cnt = N >> 7;
    const int tm = blockIdx.x / tn_cnt, tn = blockIdx.x % tn_cnt;
    const int l15 = lane & 15, lg = lane >> 4;
    const int ks = SPLIT ? blockIdx.y : 0;
    const int koff = SPLIT ? ks * Klen : 0;
    if (EPI == 3 && tn >= 8) A = A2;   // Q cols use q-input; K/V cols use kv-input

    f32x4_t acc[4][4];
#pragma unroll
    for (int i = 0; i < 4; i++)
#pragma unroll
        for (int j = 0; j < 4; j++) acc[i][j] = f32x4_t{0.f, 0.f, 0.f, 0.f};

    const int nk = Klen >> 5;
    for (int kt = 0; kt < nk; ++kt) {
#pragma unroll
        for (int i = 0; i < 2; i++) {
            const int c = i * 256 + w * 64 + lane;
            const int c0 = i * 256 + w * 64;
            const int row = c >> 2, kg = c & 3;
            gload_lds16(A + (size_t)(tm * 128 + row) * lda + koff + kt * 32 + kg * 8, &As[c0 * 8]);
        }
#pragma unroll
        for (int i = 0; i < 2; i++) {
            const int c = i * 256 + w * 64 + lane;
            const int c0 = i * 256 + w * 64;
            const int row = c >> 2, kg = c & 3;
            gload_lds16(Bw + (size_t)(tn * 128 + row) * lda + koff + kt * 32 + kg * 8, &Bs[c0 * 8]);
        }
        __syncthreads();

        bf16x8_t af[4], bfv[4];
#pragma unroll
        for (int mt = 0; mt < 4; mt++)
            af[mt] = *(const bf16x8_t*)&As[(wr * 64 + mt * 16 + l15) * 32 + lg * 8];
#pragma unroll
        for (int nt = 0; nt < 4; nt++)
            bfv[nt] = *(const bf16x8_t*)&Bs[(wc * 64 + nt * 16 + l15) * 32 + lg * 8];
#pragma unroll
        for (int mt = 0; mt < 4; mt++)
#pragma unroll
            for (int nt = 0; nt < 4; nt++)
                acc[mt][nt] = mfma16(af[mt], bfv[nt], acc[mt][nt]);
        __syncthreads();
    }

#pragma unroll
    for (int nt = 0; nt < 4; nt++) {
        const int col = tn * 128 + wc * 64 + nt * 16 + l15;
        float bv = bias[col];
        if (SPLIT && ks != 0) bv = 0.f;
#pragma unroll
        for (int mt = 0; mt < 4; mt++) {
#pragma unroll
            for (int r = 0; r < 4; r++) {
                const int row = tm * 128 + wr * 64 + mt * 16 + lg * 4 + r;
                float v = acc[mt][nt][r] + bv;
                if (EPI == 2) v = fmaxf(v, 0.f);
                if (EPI == 0) Cf[(size_t)ks * M * N + (size_t)row * N + col] = v;
                else if (EPI == 3)
                    Cb[(size_t)(col >> 10) * 4194304 + (size_t)row * 1024 + (col & 1023)] = (bf16_t)v;
                else Cb[(size_t)row * N + col] = (bf16_t)v;
            }
        }
    }
}

// ---------------------------------------------------------------------------
// Flash attention with additive bias.  One block = (b, h, 64-row q-tile),
// 4 waves; wave w owns q rows [16w,16w+16).  All LDS tiles [64][64] bf16 with
// XOR swizzle (byte ^= (row&7)<<4 on 16B chunks) to kill bank conflicts.
// ---------------------------------------------------------------------------
__global__ __launch_bounds__(256)
void attn_kernel(const bf16_t* __restrict__ Qp, const bf16_t* __restrict__ Kp,
                 const bf16_t* __restrict__ Vp, const bf16_t* __restrict__ biasb,
                 bf16_t* __restrict__ ctx) {
    __shared__ __align__(16) bf16_t Qs[64 * 64];
    __shared__ __align__(16) bf16_t Ks[64 * 64];
    __shared__ __align__(16) bf16_t Vts[64 * 64];   // V transposed: Vts[d][k]
    __shared__ __align__(16) bf16_t Ps[64 * 64];

    const int bid = blockIdx.x;
    const int qt = bid & 7, h = (bid >> 3) & 15, b = bid >> 7;
    const int t = threadIdx.x, lane = t & 63, w = t >> 6;
    const int l15 = lane & 15, lg = lane >> 4;

    // stage Q tile (swizzled)
#pragma unroll
    for (int i = 0; i < 2; i++) {
        const int c = t + i * 256;
        const int row = c >> 3, cg = c & 7;
        const uint4 v = *(const uint4*)&Qp[(((size_t)(b * LQ_ + qt * 64 + row)) * H_ + h) * DH_ + cg * 8];
        *(uint4*)((char*)Qs + row * 128 + ((cg ^ (row & 7)) << 4)) = v;
    }

    f32x4_t oacc[4];
#pragma unroll
    for (int i = 0; i < 4; i++) oacc[i] = f32x4_t{0.f, 0.f, 0.f, 0.f};
    float mrow[4] = {-1e30f, -1e30f, -1e30f, -1e30f};
    float lrow[4] = {0.f, 0.f, 0.f, 0.f};

    const bf16_t* bias_base = biasb + ((size_t)(b * H_ + h) * LQ_ + qt * 64 + w * 16) * LKV_;

    for (int kt = 0; kt < 8; ++kt) {
        __syncthreads();   // previous iteration done with Ks/Vts
#pragma unroll
        for (int i = 0; i < 2; i++) {
            const int c = t + i * 256;
            const int row = c >> 3, cg = c & 7;
            const uint4 v = *(const uint4*)&Kp[(((size_t)(b * LKV_ + kt * 64 + row)) * H_ + h) * DH_ + cg * 8];
            *(uint4*)((char*)Ks + row * 128 + ((cg ^ (row & 7)) << 4)) = v;
        }
#pragma unroll
        for (int i = 0; i < 2; i++) {
            const int c = t + i * 256;
            const int k = c >> 3, dg = c & 7;
            const bf16x8_t vv = *(const bf16x8_t*)&Vp[(((size_t)(b * LKV_ + kt * 64 + k)) * H_ + h) * DH_ + dg * 8];
#pragma unroll
            for (int j = 0; j < 8; j++) {
                const int d = dg * 8 + j;
                *(bf16_t*)((char*)Vts + d * 128 + ((((k * 2) >> 4) ^ (d & 7)) << 4) + ((k * 2) & 15)) = vv[j];
            }
        }
        __syncthreads();

        // S = Q K^T
        f32x4_t sacc[4];
#pragma unroll
        for (int i = 0; i < 4; i++) sacc[i] = f32x4_t{0.f, 0.f, 0.f, 0.f};
        bf16x8_t aq[2];
        {
            const int rowq = w * 16 + l15;
#pragma unroll
            for (int kc = 0; kc < 2; kc++)
                aq[kc] = *(const bf16x8_t*)((const char*)Qs + rowq * 128 + (((kc * 4 + lg) ^ (rowq & 7)) << 4));
        }
#pragma unroll
        for (int nt = 0; nt < 4; nt++) {
            const int rowk = nt * 16 + l15;
#pragma unroll
            for (int kc = 0; kc < 2; kc++) {
                const bf16x8_t bk = *(const bf16x8_t*)((const char*)Ks + rowk * 128 + (((kc * 4 + lg) ^ (rowk & 7)) << 4));
                sacc[nt] = mfma16(aq[kc], bk, sacc[nt]);
            }
        }

        // bias add + online softmax.  D-layout: row = 4*lg + r, col = 16*nt + l15
        const bf16_t* bb = bias_base + kt * 64;
        float esc[4];
#pragma unroll
        for (int r = 0; r < 4; r++) {
            const int qr = lg * 4 + r;
            float mx = -1e30f;
#pragma unroll
            for (int nt = 0; nt < 4; nt++) {
                const float bvv = (float)bb[(size_t)qr * LKV_ + nt * 16 + l15];
                const float v = sacc[nt][r] * 0.125f + bvv;
                sacc[nt][r] = v;
                mx = fmaxf(mx, v);
            }
#pragma unroll
            for (int msk = 8; msk >= 1; msk >>= 1) mx = fmaxf(mx, __shfl_xor(mx, msk));
            const float mnew = fmaxf(mrow[r], mx);
            esc[r] = __expf(mrow[r] - mnew);
            mrow[r] = mnew;
            float rs = 0.f;
#pragma unroll
            for (int nt = 0; nt < 4; nt++) {
                const float p = __expf(sacc[nt][r] - mnew);
                sacc[nt][r] = p;
                rs += p;
            }
#pragma unroll
            for (int msk = 8; msk >= 1; msk >>= 1) rs += __shfl_xor(rs, msk);
            lrow[r] = lrow[r] * esc[r] + rs;
        }

        // write P (bf16) into own wave strip of Ps
#pragma unroll
        for (int r = 0; r < 4; r++) {
            const int prow = w * 16 + lg * 4 + r;
#pragma unroll
            for (int nt = 0; nt < 4; nt++) {
                const int pc2 = (nt * 16 + l15) * 2;
                *(bf16_t*)((char*)Ps + prow * 128 + (((pc2 >> 4) ^ (prow & 7)) << 4) + (pc2 & 15)) =
                    (bf16_t)sacc[nt][r];
            }
        }
        asm volatile("s_waitcnt lgkmcnt(0)" ::: "memory");
        __builtin_amdgcn_sched_barrier(0);

        // rescale O then accumulate P @ V
#pragma unroll
        for (int dt = 0; dt < 4; dt++)
#pragma unroll
            for (int r = 0; r < 4; r++) oacc[dt][r] *= esc[r];

        bf16x8_t pa[2];
        {
            const int rowp = w * 16 + l15;
#pragma unroll
            for (int kc = 0; kc < 2; kc++)
                pa[kc] = *(const bf16x8_t*)((const char*)Ps + rowp * 128 + (((kc * 4 + lg) ^ (rowp & 7)) << 4));
        }
#pragma unroll
        for (int dt = 0; dt < 4; dt++) {
            const int rowv = dt * 16 + l15;
#pragma unroll
            for (int kc = 0; kc < 2; kc++) {
                const bf16x8_t bv = *(const bf16x8_t*)((const char*)Vts + rowv * 128 + (((kc * 4 + lg) ^ (rowv & 7)) << 4));
                oacc[dt] = mfma16(pa[kc], bv, oacc[dt]);
            }
        }
    }

#pragma unroll
    for (int dt = 0; dt < 4; dt++) {
#pragma unroll
        for (int r = 0; r < 4; r++) {
            const float v = oacc[dt][r] / lrow[r];
            const int q = qt * 64 + w * 16 + lg * 4 + r;
            const int d = dt * 16 + l15;
            ctx[(((size_t)(b * LQ_ + q)) * H_ + h) * DH_ + d] = (bf16_t)v;
        }
    }
}

// ---------------------------------------------------------------------------
// out = LayerNorm(X + Y0 + Y1) * g + b ; optional bf16 copy.  One block per row.
// ---------------------------------------------------------------------------
__global__ __launch_bounds__(256)
void add_ln3_kernel(const float* __restrict__ X, const float* __restrict__ Y0,
                    const float* __restrict__ Y1,
                    const float* __restrict__ g, const float* __restrict__ be,
                    float* __restrict__ of, bf16_t* __restrict__ ob) {
    const int row = blockIdx.x, t = threadIdx.x;
    const float4 xv = ((const float4*)(X + (size_t)row * 1024))[t];
    const float4 y0 = ((const float4*)(Y0 + (size_t)row * 1024))[t];
    const float4 y1 = ((const float4*)(Y1 + (size_t)row * 1024))[t];
    float v[4] = {xv.x + y0.x + y1.x, xv.y + y0.y + y1.y,
                  xv.z + y0.z + y1.z, xv.w + y0.w + y1.w};
    float s = v[0] + v[1] + v[2] + v[3];
    float s2 = v[0] * v[0] + v[1] * v[1] + v[2] * v[2] + v[3] * v[3];
#pragma unroll
    for (int m = 32; m >= 1; m >>= 1) { s += __shfl_xor(s, m); s2 += __shfl_xor(s2, m); }
    __shared__ float red[8];
    const int w = t >> 6, lane = t & 63;
    if (lane == 0) { red[w] = s; red[4 + w] = s2; }
    __syncthreads();
    s = red[0] + red[1] + red[2] + red[3];
    s2 = red[4] + red[5] + red[6] + red[7];
    const float mu = s * (1.f / 1024.f);
    const float var = s2 * (1.f / 1024.f) - mu * mu;
    const float rstd = rsqrtf(var + 1e-6f);
    const float4 gv = ((const float4*)g)[t];
    const float4 bv = ((const float4*)be)[t];
    float o[4];
    o[0] = (v[0] - mu) * rstd * gv.x + bv.x;
    o[1] = (v[1] - mu) * rstd * gv.y + bv.y;
    o[2] = (v[2] - mu) * rstd * gv.z + bv.z;
    o[3] = (v[3] - mu) * rstd * gv.w + bv.w;
    ((float4*)(of + (size_t)row * 1024))[t] = make_float4(o[0], o[1], o[2], o[3]);
    if (ob) {
        bf16x4_t qo;
        qo[0] = (bf16_t)o[0]; qo[1] = (bf16_t)o[1]; qo[2] = (bf16_t)o[2]; qo[3] = (bf16_t)o[3];
        ((bf16x4_t*)(ob + (size_t)row * 1024))[t] = qo;
    }
}

// ---------------------------------------------------------------------------
extern "C" void kernel_launch(void* const* d_in, const int* in_sizes, int n_in,
                              void* d_out, int out_size, void* d_ws, size_t ws_size,
                              hipStream_t stream) {
    (void)in_sizes; (void)n_in; (void)out_size; (void)ws_size;
    const float* q    = (const float*)d_in[0];
    const float* kv   = (const float*)d_in[1];
    const float* amap = (const float*)d_in[2];
    const float* Wq = (const float*)d_in[3];  const float* bQ = (const float*)d_in[4];
    const float* Wk = (const float*)d_in[5];  const float* bK = (const float*)d_in[6];
    const float* Wv = (const float*)d_in[7];  const float* bV = (const float*)d_in[8];
    const float* Wm = (const float*)d_in[9];  const float* bM = (const float*)d_in[10];
    const float* Wc1 = (const float*)d_in[11]; const float* bc1 = (const float*)d_in[12];
    const float* Wc2 = (const float*)d_in[13]; const float* bc2 = (const float*)d_in[14];
    const float* Wf1 = (const float*)d_in[15]; const float* bf1 = (const float*)d_in[16];
    const float* Wf2 = (const float*)d_in[17]; const float* bf2 = (const float*)d_in[18];
    const float* g1 = (const float*)d_in[19]; const float* b1 = (const float*)d_in[20];
    const float* g2 = (const float*)d_in[21]; const float* b2 = (const float*)d_in[22];

    char* w = (char*)d_ws;
    // region [0, 67108864): biasb; later p0/p1; later hb + f0/f1
    bf16_t* biasb = (bf16_t*)(w);
    float*  p0    = (float*)(w);                    // 16 MB (after attn)
    float*  p1    = (float*)(w + 16777216);         // 16 MB
    bf16_t* hb    = (bf16_t*)(w);                   // 32 MB (after add_ln3 #1)
    float*  f0    = (float*)(w + 33554432);         // 16 MB
    float*  f1    = (float*)(w + 50331648);         // 16 MB
    bf16_t* qb   = (bf16_t*)(w + 67108864);         // 8 MB ; ctx after QKV
    bf16_t* kvb  = (bf16_t*)(w + 75497472);         // 8 MB
    bf16_t* Qp   = (bf16_t*)(w + 83886080);         // 8 MB each, Q|K|V contiguous
    bf16_t* Kp   = (bf16_t*)(w + 92274688);
    bf16_t* Vp   = (bf16_t*)(w + 100663296);
    bf16_t* Wqkvb = (bf16_t*)(w + 109051904);       // 6 MB (Wq|Wk|Wv bf16)
    bf16_t* Wmb  = (bf16_t*)(w + 115343360);        // 2 MB
    bf16_t* Wf1b = (bf16_t*)(w + 117440512);        // 8 MB
    bf16_t* Wf2b = (bf16_t*)(w + 125829120);        // 8 MB
    float*  bqkv = (float*)(w + 134217728);         // 12 KB
    bf16_t* ctx = qb;                               // qb dead after QKV gemm
    float*  xf  = (float*)Qp;                       // 16 MB over Qp+Kp (dead after attn)
    bf16_t* xb  = Vp;                               // Vp dead after attn

    dim3 blk(256);
    cvt_bf16_kernel<<<4096, blk, 0, stream>>>(q,   qb,   1048576);
    cvt_bf16_kernel<<<4096, blk, 0, stream>>>(kv,  kvb,  1048576);
    cvt_bf16_kernel<<<1024, blk, 0, stream>>>(Wq,  Wqkvb,           262144);
    cvt_bf16_kernel<<<1024, blk, 0, stream>>>(Wk,  Wqkvb + 1048576, 262144);
    cvt_bf16_kernel<<<1024, blk, 0, stream>>>(Wv,  Wqkvb + 2097152, 262144);
    cvt_bf16_kernel<<<1024, blk, 0, stream>>>(Wm,  Wmb,  262144);
    cvt_bf16_kernel<<<4096, blk, 0, stream>>>(Wf1, Wf1b, 1048576);
    cvt_bf16_kernel<<<4096, blk, 0, stream>>>(Wf2, Wf2b, 1048576);
    pack3_kernel<<<4, blk, 0, stream>>>(bQ, bK, bV, bqkv);

    bias_mlp_mfma<<<8192, blk, 0, stream>>>(amap, Wc1, bc1, Wc2, bc2, biasb);

    // fused QKV projection: N=3072, A chosen per column block (q for cols<1024)
    gemm_bt<3, false><<<768, blk, 0, stream>>>(qb, kvb, Wqkvb, bqkv, nullptr, Qp,
                                               4096, 3072, 1024, 1024);

    attn_kernel<<<1024, blk, 0, stream>>>(Qp, Kp, Vp, biasb, ctx);

    // out-proj, split-K=2 -> p0,p1 (overwrites biasb region, dead now)
    gemm_bt<0, true><<<dim3(256, 2), blk, 0, stream>>>(ctx, nullptr, Wmb, bM, p0, nullptr,
                                                       4096, 1024, 512, 1024);
    add_ln3_kernel<<<4096, blk, 0, stream>>>(q, p0, p1, g1, b1, xf, xb);

    // FFN1 (relu, bf16) -> hb
    gemm_bt<2, false><<<1024, blk, 0, stream>>>(xb, nullptr, Wf1b, bf1, nullptr, hb,
                                                4096, 4096, 1024, 1024);
    // FFN2, split-K=2 -> f0,f1
    gemm_bt<0, true><<<dim3(256, 2), blk, 0, stream>>>(hb, nullptr, Wf2b, bf2, f0, nullptr,
                                                       4096, 1024, 2048, 4096);
    add_ln3_kernel<<<4096, blk, 0, stream>>>(xf, f0, f1, g2, b2, (float*)d_out, nullptr);
}

// Round 5
// 376.457 us; speedup vs baseline: 1.3970x; 1.0655x over previous
//
#include <hip/hip_runtime.h>
#include <hip/hip_bf16.h>

typedef __bf16 bf16_t;
typedef __bf16 bf16x4_t __attribute__((ext_vector_type(4)));
typedef __bf16 bf16x8_t __attribute__((ext_vector_type(8)));
typedef float  f32x4_t  __attribute__((ext_vector_type(4)));

#define B_   8
#define LQ_  512
#define LKV_ 512
#define D_   1024
#define H_   16
#define DH_  64
#define FF_  4096

__device__ __forceinline__ f32x4_t mfma16(bf16x8_t a, bf16x8_t b, f32x4_t c) {
    return __builtin_amdgcn_mfma_f32_16x16x32_bf16(a, b, c, 0, 0, 0);
}

__device__ __forceinline__ void gload_lds16(const bf16_t* g, bf16_t* l) {
    __builtin_amdgcn_global_load_lds(
        (const __attribute__((address_space(1))) void*)g,
        (__attribute__((address_space(3))) void*)l, 16, 0, 0);
}

// exact-GELU via A&S 7.1.26 erf (|eps|<=1.5e-7) with fast rcp (no div sequence)
__device__ __forceinline__ float gelu_exact(float h) {
    const float z  = h * 0.70710678118654752f;
    const float az = fabsf(z);
    const float t1 = __builtin_amdgcn_rcpf(fmaf(az, 0.3275911f, 1.f));
    float poly = fmaf(1.061405429f, t1, -1.453152027f);
    poly = fmaf(poly, t1, 1.421413741f);
    poly = fmaf(poly, t1, -0.284496736f);
    poly = fmaf(poly, t1, 0.254829592f);
    poly *= t1;
    const float e = __expf(-z * z);
    float erfa = fmaf(-poly, e, 1.f);            // erf(|z|)
    erfa = (h >= 0.f) ? erfa : -erfa;
    const float th = 0.5f * h;
    return fmaf(th, erfa, th);
}

// ---------------------------------------------------------------------------
// f32 -> bf16 convert (vectorized)
// ---------------------------------------------------------------------------
__global__ __launch_bounds__(256)
void cvt_bf16_kernel(const float* __restrict__ in, bf16_t* __restrict__ out, int n4) {
    const int i = blockIdx.x * 256 + threadIdx.x;
    if (i >= n4) return;
    const float4 v = ((const float4*)in)[i];
    bf16x4_t o;
    o[0] = (bf16_t)v.x; o[1] = (bf16_t)v.y; o[2] = (bf16_t)v.z; o[3] = (bf16_t)v.w;
    ((bf16x4_t*)out)[i] = o;
}

__global__ __launch_bounds__(256)
void pack3_kernel(const float* __restrict__ a, const float* __restrict__ b,
                  const float* __restrict__ c, float* __restrict__ o) {
    const int i = blockIdx.x * 256 + threadIdx.x;   // grid 4 -> i < 1024
    o[i] = a[i]; o[1024 + i] = b[i]; o[2048 + i] = c[i];
}

// ---------------------------------------------------------------------------
// AttentionBiasMLP via MFMA.  One wave handles 64 consecutive positions
// (same b,q; k = k0..k0+63).  Wave-private LDS; no block barriers.
// W1 is prescaled by ln2 so inputs use raw log2.
// ---------------------------------------------------------------------------
__global__ __launch_bounds__(256)
void bias_mlp_mfma(const float* __restrict__ amap,
                   const float* __restrict__ Wc1, const float* __restrict__ bc1,
                   const float* __restrict__ Wc2, const float* __restrict__ bc2,
                   bf16_t* __restrict__ biasb) {
    __shared__ __align__(16) char lds[4][8192];  // per wave: Xs [0,3072) rows 48B; Hs [3072,8192) rows 80B
    const int t = threadIdx.x, lane = t & 63, w = t >> 6;
    const int l15 = lane & 15, lg = lane >> 4;
    char* Xs = lds[w];
    char* Hs = lds[w] + 3072;

    // --- weight fragments (registers, once).  W1 *= ln2 (log2 input fold) ---
    bf16x8_t b1f[2], b2f;
    f32x4_t bc1v[2];
#pragma unroll
    for (int ot = 0; ot < 2; ot++) {
        bf16x8_t v;
#pragma unroll
        for (int i = 0; i < 8; i++) {
            const int kk = (lg * 8 + i) & 15;                       // in-bounds always
            const float wv = Wc1[(ot * 16 + l15) * 16 + kk] * 0.69314718055994531f;
            v[i] = (lg < 2) ? (bf16_t)wv : (bf16_t)0.f;             // zero-pad K 16->32
        }
        b1f[ot] = v;
        const float bb = bc1[ot * 16 + l15];
        bc1v[ot] = f32x4_t{bb, bb, bb, bb};
    }
    {
        bf16x8_t v;
#pragma unroll
        for (int i = 0; i < 8; i++) v[i] = (bf16_t)Wc2[l15 * 32 + lg * 8 + i];
        b2f = v;
    }
    const float bc2s = bc2[l15];
    const f32x4_t cinit2 = f32x4_t{bc2s, bc2s, bc2s, bc2s};

    // --- positions ---
    const int posb = (blockIdx.x * 4 + w) * 64;
    const int b  = posb >> 18;
    const int q  = (posb >> 9) & 511;
    const int k0 = posb & 511;

    // --- load 16 channels, log2, stage to LDS (row = lane, 16 bf16, stride 48B) ---
    const float* src = amap + (size_t)(b * 16) * 263169 + (size_t)(q + 1) * 513 + (k0 + 1 + lane);
    bf16_t xr[16];
#pragma unroll
    for (int c = 0; c < 16; c++) {
        const float v = src[(size_t)c * 263169];
        xr[c] = (bf16_t)__log2f(v + 1e-6f);
    }
    *(bf16x8_t*)(Xs + lane * 48)      = *(bf16x8_t*)&xr[0];
    *(bf16x8_t*)(Xs + lane * 48 + 16) = *(bf16x8_t*)&xr[8];

    // --- layer 1 MFMA: A-frag row=l15 (pos); lg>=2 lanes re-read valid bytes, B=0 there ---
    const int lgm16 = (lg & 1) * 16;
    f32x4_t h1[4][2];
#pragma unroll
    for (int p = 0; p < 4; p++) {
        const bf16x8_t a1 = *(const bf16x8_t*)(Xs + (p * 16 + l15) * 48 + lgm16);
#pragma unroll
        for (int ot = 0; ot < 2; ot++)
            h1[p][ot] = mfma16(a1, b1f[ot], bc1v[ot]);
    }

    // --- GELU, write H to LDS [64][40bf16] ---
#pragma unroll
    for (int p = 0; p < 4; p++)
#pragma unroll
        for (int ot = 0; ot < 2; ot++)
#pragma unroll
            for (int r = 0; r < 4; r++) {
                const float g = gelu_exact(h1[p][ot][r]);
                *(bf16_t*)(Hs + (p * 16 + lg * 4 + r) * 80 + (ot * 16 + l15) * 2) = (bf16_t)g;
            }

    // --- layer 2 MFMA + direct bf16x4 store (C rows are 4 consecutive k) ---
    const size_t obase = ((size_t)(b * 16 + l15) * 512 + q) * 512 + k0;
#pragma unroll
    for (int p = 0; p < 4; p++) {
        const bf16x8_t a2 = *(const bf16x8_t*)(Hs + (p * 16 + l15) * 80 + lg * 16);
        const f32x4_t o2 = mfma16(a2, b2f, cinit2);
        bf16x4_t ov;
#pragma unroll
        for (int r = 0; r < 4; r++) ov[r] = (bf16_t)o2[r];
        *(bf16x4_t*)&biasb[obase + p * 16 + lg * 4] = ov;
    }
}

// ---------------------------------------------------------------------------
// bf16 GEMM: C[M,N] = A[M,K] @ W[N,K]^T + bias   (m97 structure: 128x128 tile,
// BK=32, global_load_lds staging, 4 waves 2x2, 16x16x32 MFMA)
// EPI: 0 = f32 out, 1 = bf16 out, 2 = relu -> bf16 out, 3 = QKV fused bf16 out
//      (EPI 3 scales Q columns by 1/sqrt(DH) = 0.125 -- exact pow2 scale)
// SPLIT: blockIdx.y selects K-half; f32 partials at Cf + ks*M*N; bias on ks==0
// ---------------------------------------------------------------------------
template <int EPI, bool SPLIT>
__global__ __launch_bounds__(256)
void gemm_bt(const bf16_t* __restrict__ A, const bf16_t* __restrict__ A2,
             const bf16_t* __restrict__ Bw,
             const float* __restrict__ bias, float* __restrict__ Cf,
             bf16_t* __restrict__ Cb, int M, int N, int Klen, int lda) {
    __shared__ __align__(16) bf16_t As[128 * 32];
    __shared__ __align__(16) bf16_t Bs[128 * 32];
    const int t = threadIdx.x, lane = t & 63, w = t >> 6;
    const int wr = w >> 1, wc = w & 1;
    const int tn_cnt = N >> 7;
    const int tm = blockIdx.x / tn_cnt, tn = blockIdx.x % tn_cnt;
    const int l15 = lane & 15, lg = lane >> 4;
    const int ks = SPLIT ? blockIdx.y : 0;
    const int koff = SPLIT ? ks * Klen : 0;
    if (EPI == 3 && tn >= 8) A = A2;   // Q cols use q-input; K/V cols use kv-input

    f32x4_t acc[4][4];
#pragma unroll
    for (int i = 0; i < 4; i++)
#pragma unroll
        for (int j = 0; j < 4; j++) acc[i][j] = f32x4_t{0.f, 0.f, 0.f, 0.f};

    const int nk = Klen >> 5;
    for (int kt = 0; kt < nk; ++kt) {
#pragma unroll
        for (int i = 0; i < 2; i++) {
            const int c = i * 256 + w * 64 + lane;
            const int c0 = i * 256 + w * 64;
            const int row = c >> 2, kg = c & 3;
            gload_lds16(A + (size_t)(tm * 128 + row) * lda + koff + kt * 32 + kg * 8, &As[c0 * 8]);
        }
#pragma unroll
        for (int i = 0; i < 2; i++) {
            const int c = i * 256 + w * 64 + lane;
            const int c0 = i * 256 + w * 64;
            const int row = c >> 2, kg = c & 3;
            gload_lds16(Bw + (size_t)(tn * 128 + row) * lda + koff + kt * 32 + kg * 8, &Bs[c0 * 8]);
        }
        __syncthreads();

        bf16x8_t af[4], bfv[4];
#pragma unroll
        for (int mt = 0; mt < 4; mt++)
            af[mt] = *(const bf16x8_t*)&As[(wr * 64 + mt * 16 + l15) * 32 + lg * 8];
#pragma unroll
        for (int nt = 0; nt < 4; nt++)
            bfv[nt] = *(const bf16x8_t*)&Bs[(wc * 64 + nt * 16 + l15) * 32 + lg * 8];
#pragma unroll
        for (int mt = 0; mt < 4; mt++)
#pragma unroll
            for (int nt = 0; nt < 4; nt++)
                acc[mt][nt] = mfma16(af[mt], bfv[nt], acc[mt][nt]);
        __syncthreads();
    }

#pragma unroll
    for (int nt = 0; nt < 4; nt++) {
        const int col = tn * 128 + wc * 64 + nt * 16 + l15;
        float bv = bias[col];
        if (SPLIT && ks != 0) bv = 0.f;
#pragma unroll
        for (int mt = 0; mt < 4; mt++) {
#pragma unroll
            for (int r = 0; r < 4; r++) {
                const int row = tm * 128 + wr * 64 + mt * 16 + lg * 4 + r;
                float v = acc[mt][nt][r] + bv;
                if (EPI == 2) v = fmaxf(v, 0.f);
                if (EPI == 3 && tn < 8) v *= 0.125f;     // fold 1/sqrt(DH) into Q
                if (EPI == 0) Cf[(size_t)ks * M * N + (size_t)row * N + col] = v;
                else if (EPI == 3)
                    Cb[(size_t)(col >> 10) * 4194304 + (size_t)row * 1024 + (col & 1023)] = (bf16_t)v;
                else Cb[(size_t)row * N + col] = (bf16_t)v;
            }
        }
    }
}

// ---------------------------------------------------------------------------
// Flash attention with additive bias.  One block = (b, h, 64-row q-tile),
// 4 waves; wave w owns q rows [16w,16w+16).  Q/K/V/P LDS tiles XOR-swizzled;
// bias tile staged via registers (uint4 load + ds_write, linear [q][k]).
// Q is pre-scaled by 0.125 at projection time.
// ---------------------------------------------------------------------------
__global__ __launch_bounds__(256)
void attn_kernel(const bf16_t* __restrict__ Qp, const bf16_t* __restrict__ Kp,
                 const bf16_t* __restrict__ Vp, const bf16_t* __restrict__ biasb,
                 bf16_t* __restrict__ ctx) {
    __shared__ __align__(16) bf16_t Qs[64 * 64];
    __shared__ __align__(16) bf16_t Ks[64 * 64];
    __shared__ __align__(16) bf16_t Vts[64 * 64];   // V transposed: Vts[d][k]
    __shared__ __align__(16) bf16_t Ps[64 * 64];
    __shared__ __align__(16) bf16_t Bbs[64 * 64];   // bias tile, linear [q][k]

    const int bid = blockIdx.x;
    const int qt = bid & 7, h = (bid >> 3) & 15, b = bid >> 7;
    const int t = threadIdx.x, lane = t & 63, w = t >> 6;
    const int l15 = lane & 15, lg = lane >> 4;

    // stage Q tile (swizzled)
#pragma unroll
    for (int i = 0; i < 2; i++) {
        const int c = t + i * 256;
        const int row = c >> 3, cg = c & 7;
        const uint4 v = *(const uint4*)&Qp[(((size_t)(b * LQ_ + qt * 64 + row)) * H_ + h) * DH_ + cg * 8];
        *(uint4*)((char*)Qs + row * 128 + ((cg ^ (row & 7)) << 4)) = v;
    }

    f32x4_t oacc[4];
#pragma unroll
    for (int i = 0; i < 4; i++) oacc[i] = f32x4_t{0.f, 0.f, 0.f, 0.f};
    float mrow[4] = {-1e30f, -1e30f, -1e30f, -1e30f};
    float lrow[4] = {0.f, 0.f, 0.f, 0.f};

    const bf16_t* bias_tile = biasb + ((size_t)(b * H_ + h) * LQ_ + qt * 64) * LKV_;

    for (int kt = 0; kt < 8; ++kt) {
        __syncthreads();   // previous iteration done with Ks/Vts/Bbs
#pragma unroll
        for (int i = 0; i < 2; i++) {
            const int c = t + i * 256;
            const int row = c >> 3, cg = c & 7;
            const uint4 v = *(const uint4*)&Kp[(((size_t)(b * LKV_ + kt * 64 + row)) * H_ + h) * DH_ + cg * 8];
            *(uint4*)((char*)Ks + row * 128 + ((cg ^ (row & 7)) << 4)) = v;
        }
        // stage bias tile via registers (coalesced 16B, linear LDS [q][k])
#pragma unroll
        for (int i = 0; i < 2; i++) {
            const int c = t + i * 256;
            const int row = c >> 3, cg = c & 7;
            const uint4 bv4 = *(const uint4*)&bias_tile[(size_t)row * LKV_ + kt * 64 + cg * 8];
            *(uint4*)&Bbs[row * 64 + cg * 8] = bv4;
        }
#pragma unroll
        for (int i = 0; i < 2; i++) {
            const int c = t + i * 256;
            const int k = c >> 3, dg = c & 7;
            const bf16x8_t vv = *(const bf16x8_t*)&Vp[(((size_t)(b * LKV_ + kt * 64 + k)) * H_ + h) * DH_ + dg * 8];
#pragma unroll
            for (int j = 0; j < 8; j++) {
                const int d = dg * 8 + j;
                *(bf16_t*)((char*)Vts + d * 128 + ((((k * 2) >> 4) ^ (d & 7)) << 4) + ((k * 2) & 15)) = vv[j];
            }
        }
        __syncthreads();

        // S = Q K^T
        f32x4_t sacc[4];
#pragma unroll
        for (int i = 0; i < 4; i++) sacc[i] = f32x4_t{0.f, 0.f, 0.f, 0.f};
        bf16x8_t aq[2];
        {
            const int rowq = w * 16 + l15;
#pragma unroll
            for (int kc = 0; kc < 2; kc++)
                aq[kc] = *(const bf16x8_t*)((const char*)Qs + rowq * 128 + (((kc * 4 + lg) ^ (rowq & 7)) << 4));
        }
#pragma unroll
        for (int nt = 0; nt < 4; nt++) {
            const int rowk = nt * 16 + l15;
#pragma unroll
            for (int kc = 0; kc < 2; kc++) {
                const bf16x8_t bk = *(const bf16x8_t*)((const char*)Ks + rowk * 128 + (((kc * 4 + lg) ^ (rowk & 7)) << 4));
                sacc[nt] = mfma16(aq[kc], bk, sacc[nt]);
            }
        }

        // bias add + online softmax.  D-layout: row = 4*lg + r, col = 16*nt + l15
        float esc[4];
#pragma unroll
        for (int r = 0; r < 4; r++) {
            const int qr = w * 16 + lg * 4 + r;
            float mx = -1e30f;
#pragma unroll
            for (int nt = 0; nt < 4; nt++) {
                const float bvv = (float)Bbs[qr * 64 + nt * 16 + l15];
                const float v = sacc[nt][r] + bvv;
                sacc[nt][r] = v;
                mx = fmaxf(mx, v);
            }
#pragma unroll
            for (int msk = 8; msk >= 1; msk >>= 1) mx = fmaxf(mx, __shfl_xor(mx, msk));
            const float mnew = fmaxf(mrow[r], mx);
            esc[r] = __expf(mrow[r] - mnew);
            mrow[r] = mnew;
            float rs = 0.f;
#pragma unroll
            for (int nt = 0; nt < 4; nt++) {
                const float p = __expf(sacc[nt][r] - mnew);
                sacc[nt][r] = p;
                rs += p;
            }
#pragma unroll
            for (int msk = 8; msk >= 1; msk >>= 1) rs += __shfl_xor(rs, msk);
            lrow[r] = lrow[r] * esc[r] + rs;
        }

        // write P (bf16) into own wave strip of Ps
#pragma unroll
        for (int r = 0; r < 4; r++) {
            const int prow = w * 16 + lg * 4 + r;
#pragma unroll
            for (int nt = 0; nt < 4; nt++) {
                const int pc2 = (nt * 16 + l15) * 2;
                *(bf16_t*)((char*)Ps + prow * 128 + (((pc2 >> 4) ^ (prow & 7)) << 4) + (pc2 & 15)) =
                    (bf16_t)sacc[nt][r];
            }
        }
        asm volatile("s_waitcnt lgkmcnt(0)" ::: "memory");
        __builtin_amdgcn_sched_barrier(0);

        // rescale O then accumulate P @ V
#pragma unroll
        for (int dt = 0; dt < 4; dt++)
#pragma unroll
            for (int r = 0; r < 4; r++) oacc[dt][r] *= esc[r];

        bf16x8_t pa[2];
        {
            const int rowp = w * 16 + l15;
#pragma unroll
            for (int kc = 0; kc < 2; kc++)
                pa[kc] = *(const bf16x8_t*)((const char*)Ps + rowp * 128 + (((kc * 4 + lg) ^ (rowp & 7)) << 4));
        }
#pragma unroll
        for (int dt = 0; dt < 4; dt++) {
            const int rowv = dt * 16 + l15;
#pragma unroll
            for (int kc = 0; kc < 2; kc++) {
                const bf16x8_t bv = *(const bf16x8_t*)((const char*)Vts + rowv * 128 + (((kc * 4 + lg) ^ (rowv & 7)) << 4));
                oacc[dt] = mfma16(pa[kc], bv, oacc[dt]);
            }
        }
    }

    float inv[4];
#pragma unroll
    for (int r = 0; r < 4; r++) inv[r] = __builtin_amdgcn_rcpf(lrow[r]);
#pragma unroll
    for (int dt = 0; dt < 4; dt++) {
#pragma unroll
        for (int r = 0; r < 4; r++) {
            const float v = oacc[dt][r] * inv[r];
            const int q = qt * 64 + w * 16 + lg * 4 + r;
            const int d = dt * 16 + l15;
            ctx[(((size_t)(b * LQ_ + q)) * H_ + h) * DH_ + d] = (bf16_t)v;
        }
    }
}

// ---------------------------------------------------------------------------
// out = LayerNorm(X + Y0 + Y1) * g + b ; optional bf16 copy.  One block per row.
// ---------------------------------------------------------------------------
__global__ __launch_bounds__(256)
void add_ln3_kernel(const float* __restrict__ X, const float* __restrict__ Y0,
                    const float* __restrict__ Y1,
                    const float* __restrict__ g, const float* __restrict__ be,
                    float* __restrict__ of, bf16_t* __restrict__ ob) {
    const int row = blockIdx.x, t = threadIdx.x;
    const float4 xv = ((const float4*)(X + (size_t)row * 1024))[t];
    const float4 y0 = ((const float4*)(Y0 + (size_t)row * 1024))[t];
    const float4 y1 = ((const float4*)(Y1 + (size_t)row * 1024))[t];
    float v[4] = {xv.x + y0.x + y1.x, xv.y + y0.y + y1.y,
                  xv.z + y0.z + y1.z, xv.w + y0.w + y1.w};
    float s = v[0] + v[1] + v[2] + v[3];
    float s2 = v[0] * v[0] + v[1] * v[1] + v[2] * v[2] + v[3] * v[3];
#pragma unroll
    for (int m = 32; m >= 1; m >>= 1) { s += __shfl_xor(s, m); s2 += __shfl_xor(s2, m); }
    __shared__ float red[8];
    const int w = t >> 6, lane = t & 63;
    if (lane == 0) { red[w] = s; red[4 + w] = s2; }
    __syncthreads();
    s = red[0] + red[1] + red[2] + red[3];
    s2 = red[4] + red[5] + red[6] + red[7];
    const float mu = s * (1.f / 1024.f);
    const float var = s2 * (1.f / 1024.f) - mu * mu;
    const float rstd = rsqrtf(var + 1e-6f);
    const float4 gv = ((const float4*)g)[t];
    const float4 bv = ((const float4*)be)[t];
    float o[4];
    o[0] = (v[0] - mu) * rstd * gv.x + bv.x;
    o[1] = (v[1] - mu) * rstd * gv.y + bv.y;
    o[2] = (v[2] - mu) * rstd * gv.z + bv.z;
    o[3] = (v[3] - mu) * rstd * gv.w + bv.w;
    ((float4*)(of + (size_t)row * 1024))[t] = make_float4(o[0], o[1], o[2], o[3]);
    if (ob) {
        bf16x4_t qo;
        qo[0] = (bf16_t)o[0]; qo[1] = (bf16_t)o[1]; qo[2] = (bf16_t)o[2]; qo[3] = (bf16_t)o[3];
        ((bf16x4_t*)(ob + (size_t)row * 1024))[t] = qo;
    }
}

// ---------------------------------------------------------------------------
extern "C" void kernel_launch(void* const* d_in, const int* in_sizes, int n_in,
                              void* d_out, int out_size, void* d_ws, size_t ws_size,
                              hipStream_t stream) {
    (void)in_sizes; (void)n_in; (void)out_size; (void)ws_size;
    const float* q    = (const float*)d_in[0];
    const float* kv   = (const float*)d_in[1];
    const float* amap = (const float*)d_in[2];
    const float* Wq = (const float*)d_in[3];  const float* bQ = (const float*)d_in[4];
    const float* Wk = (const float*)d_in[5];  const float* bK = (const float*)d_in[6];
    const float* Wv = (const float*)d_in[7];  const float* bV = (const float*)d_in[8];
    const float* Wm = (const float*)d_in[9];  const float* bM = (const float*)d_in[10];
    const float* Wc1 = (const float*)d_in[11]; const float* bc1 = (const float*)d_in[12];
    const float* Wc2 = (const float*)d_in[13]; const float* bc2 = (const float*)d_in[14];
    const float* Wf1 = (const float*)d_in[15]; const float* bf1 = (const float*)d_in[16];
    const float* Wf2 = (const float*)d_in[17]; const float* bf2 = (const float*)d_in[18];
    const float* g1 = (const float*)d_in[19]; const float* b1 = (const float*)d_in[20];
    const float* g2 = (const float*)d_in[21]; const float* b2 = (const float*)d_in[22];

    char* w = (char*)d_ws;
    // region [0, 67108864): biasb; later p0/p1; later hb + f0/f1
    bf16_t* biasb = (bf16_t*)(w);
    float*  p0    = (float*)(w);                    // 16 MB (after attn)
    float*  p1    = (float*)(w + 16777216);         // 16 MB
    bf16_t* hb    = (bf16_t*)(w);                   // 32 MB (after add_ln3 #1)
    float*  f0    = (float*)(w + 33554432);         // 16 MB
    float*  f1    = (float*)(w + 50331648);         // 16 MB
    bf16_t* qb   = (bf16_t*)(w + 67108864);         // 8 MB ; ctx after QKV
    bf16_t* kvb  = (bf16_t*)(w + 75497472);         // 8 MB
    bf16_t* Qp   = (bf16_t*)(w + 83886080);         // 8 MB each, Q|K|V contiguous
    bf16_t* Kp   = (bf16_t*)(w + 92274688);
    bf16_t* Vp   = (bf16_t*)(w + 100663296);
    bf16_t* Wqkvb = (bf16_t*)(w + 109051904);       // 6 MB (Wq|Wk|Wv bf16)
    bf16_t* Wmb  = (bf16_t*)(w + 115343360);        // 2 MB
    bf16_t* Wf1b = (bf16_t*)(w + 117440512);        // 8 MB
    bf16_t* Wf2b = (bf16_t*)(w + 125829120);        // 8 MB
    float*  bqkv = (float*)(w + 134217728);         // 12 KB
    bf16_t* ctx = qb;                               // qb dead after QKV gemm
    float*  xf  = (float*)Qp;                       // 16 MB over Qp+Kp (dead after attn)
    bf16_t* xb  = Vp;                               // Vp dead after attn

    dim3 blk(256);
    cvt_bf16_kernel<<<4096, blk, 0, stream>>>(q,   qb,   1048576);
    cvt_bf16_kernel<<<4096, blk, 0, stream>>>(kv,  kvb,  1048576);
    cvt_bf16_kernel<<<1024, blk, 0, stream>>>(Wq,  Wqkvb,           262144);
    cvt_bf16_kernel<<<1024, blk, 0, stream>>>(Wk,  Wqkvb + 1048576, 262144);
    cvt_bf16_kernel<<<1024, blk, 0, stream>>>(Wv,  Wqkvb + 2097152, 262144);
    cvt_bf16_kernel<<<1024, blk, 0, stream>>>(Wm,  Wmb,  262144);
    cvt_bf16_kernel<<<4096, blk, 0, stream>>>(Wf1, Wf1b, 1048576);
    cvt_bf16_kernel<<<4096, blk, 0, stream>>>(Wf2, Wf2b, 1048576);
    pack3_kernel<<<4, blk, 0, stream>>>(bQ, bK, bV, bqkv);

    bias_mlp_mfma<<<8192, blk, 0, stream>>>(amap, Wc1, bc1, Wc2, bc2, biasb);

    // fused QKV projection: N=3072, A chosen per column block (q for cols<1024)
    gemm_bt<3, false><<<768, blk, 0, stream>>>(qb, kvb, Wqkvb, bqkv, nullptr, Qp,
                                               4096, 3072, 1024, 1024);

    attn_kernel<<<1024, blk, 0, stream>>>(Qp, Kp, Vp, biasb, ctx);

    // out-proj, split-K=2 -> p0,p1 (overwrites biasb region, dead now)
    gemm_bt<0, true><<<dim3(256, 2), blk, 0, stream>>>(ctx, nullptr, Wmb, bM, p0, nullptr,
                                                       4096, 1024, 512, 1024);
    add_ln3_kernel<<<4096, blk, 0, stream>>>(q, p0, p1, g1, b1, xf, xb);

    // FFN1 (relu, bf16) -> hb
    gemm_bt<2, false><<<1024, blk, 0, stream>>>(xb, nullptr, Wf1b, bf1, nullptr, hb,
                                                4096, 4096, 1024, 1024);
    // FFN2, split-K=2 -> f0,f1
    gemm_bt<0, true><<<dim3(256, 2), blk, 0, stream>>>(hb, nullptr, Wf2b, bf2, f0, nullptr,
                                                       4096, 1024, 2048, 4096);
    add_ln3_kernel<<<4096, blk, 0, stream>>>(xf, f0, f1, g2, b2, (float*)d_out, nullptr);
}

// Round 6
// 364.133 us; speedup vs baseline: 1.4443x; 1.0338x over previous
//
#include <hip/hip_runtime.h>
#include <hip/hip_bf16.h>

typedef __bf16 bf16_t;
typedef __bf16 bf16x4_t __attribute__((ext_vector_type(4)));
typedef __bf16 bf16x8_t __attribute__((ext_vector_type(8)));
typedef float  f32x4_t  __attribute__((ext_vector_type(4)));

#define B_   8
#define LQ_  512
#define LKV_ 512
#define D_   1024
#define H_   16
#define DH_  64
#define FF_  4096

__device__ __forceinline__ f32x4_t mfma16(bf16x8_t a, bf16x8_t b, f32x4_t c) {
    return __builtin_amdgcn_mfma_f32_16x16x32_bf16(a, b, c, 0, 0, 0);
}

__device__ __forceinline__ void gload_lds16(const bf16_t* g, bf16_t* l) {
    __builtin_amdgcn_global_load_lds(
        (const __attribute__((address_space(1))) void*)g,
        (__attribute__((address_space(3))) void*)l, 16, 0, 0);
}

// bijective XCD chunking: blocks with pid%8==x (same XCD, HW round-robin)
// get a CONTIGUOUS range of work indices.  Requires nwg % 8 == 0.
__device__ __forceinline__ int xcd_swz(int pid, int nwg) {
    return (pid & 7) * (nwg >> 3) + (pid >> 3);
}

// fast GELU: h * sigmoid(1.702 h).  |err| <= ~0.02 absolute -> ~0.002 on the
// attn logits after W2 (rms 0.02, 32 terms) -- far under the 0.1 threshold.
__device__ __forceinline__ float gelu_fast(float h) {
    const float e = exp2f(h * -2.45546696f);     // exp(-1.702 h)
    return h * __builtin_amdgcn_rcpf(1.f + e);
}

// ---------------------------------------------------------------------------
// f32 -> bf16 convert (vectorized)
// ---------------------------------------------------------------------------
__global__ __launch_bounds__(256)
void cvt_bf16_kernel(const float* __restrict__ in, bf16_t* __restrict__ out, int n4) {
    const int i = blockIdx.x * 256 + threadIdx.x;
    if (i >= n4) return;
    const float4 v = ((const float4*)in)[i];
    bf16x4_t o;
    o[0] = (bf16_t)v.x; o[1] = (bf16_t)v.y; o[2] = (bf16_t)v.z; o[3] = (bf16_t)v.w;
    ((bf16x4_t*)out)[i] = o;
}

__global__ __launch_bounds__(256)
void pack3_kernel(const float* __restrict__ a, const float* __restrict__ b,
                  const float* __restrict__ c, float* __restrict__ o) {
    const int i = blockIdx.x * 256 + threadIdx.x;   // grid 4 -> i < 1024
    o[i] = a[i]; o[1024 + i] = b[i]; o[2048 + i] = c[i];
}

// ---------------------------------------------------------------------------
// AttentionBiasMLP via MFMA.  One wave handles 64 consecutive positions
// (same b,q; k = k0..k0+63).  Wave-private LDS; no block barriers.
// W1 is prescaled by ln2 so inputs use raw log2.
// ---------------------------------------------------------------------------
__global__ __launch_bounds__(256)
void bias_mlp_mfma(const float* __restrict__ amap,
                   const float* __restrict__ Wc1, const float* __restrict__ bc1,
                   const float* __restrict__ Wc2, const float* __restrict__ bc2,
                   bf16_t* __restrict__ biasb) {
    __shared__ __align__(16) char lds[4][8192];  // per wave: Xs [0,3072) rows 48B; Hs [3072,8192) rows 80B
    const int t = threadIdx.x, lane = t & 63, w = t >> 6;
    const int l15 = lane & 15, lg = lane >> 4;
    char* Xs = lds[w];
    char* Hs = lds[w] + 3072;

    // --- weight fragments (registers, once).  W1 *= ln2 (log2 input fold) ---
    bf16x8_t b1f[2], b2f;
    f32x4_t bc1v[2];
#pragma unroll
    for (int ot = 0; ot < 2; ot++) {
        bf16x8_t v;
#pragma unroll
        for (int i = 0; i < 8; i++) {
            const int kk = (lg * 8 + i) & 15;                       // in-bounds always
            const float wv = Wc1[(ot * 16 + l15) * 16 + kk] * 0.69314718055994531f;
            v[i] = (lg < 2) ? (bf16_t)wv : (bf16_t)0.f;             // zero-pad K 16->32
        }
        b1f[ot] = v;
        const float bb = bc1[ot * 16 + l15];
        bc1v[ot] = f32x4_t{bb, bb, bb, bb};
    }
    {
        bf16x8_t v;
#pragma unroll
        for (int i = 0; i < 8; i++) v[i] = (bf16_t)Wc2[l15 * 32 + lg * 8 + i];
        b2f = v;
    }
    const float bc2s = bc2[l15];
    const f32x4_t cinit2 = f32x4_t{bc2s, bc2s, bc2s, bc2s};

    // --- positions ---
    const int posb = (blockIdx.x * 4 + w) * 64;
    const int b  = posb >> 18;
    const int q  = (posb >> 9) & 511;
    const int k0 = posb & 511;

    // --- load 16 channels, log2, stage to LDS (row = lane, 16 bf16, stride 48B) ---
    const float* src = amap + (size_t)(b * 16) * 263169 + (size_t)(q + 1) * 513 + (k0 + 1 + lane);
    bf16_t xr[16];
#pragma unroll
    for (int c = 0; c < 16; c++) {
        const float v = src[(size_t)c * 263169];
        xr[c] = (bf16_t)__log2f(v + 1e-6f);
    }
    *(bf16x8_t*)(Xs + lane * 48)      = *(bf16x8_t*)&xr[0];
    *(bf16x8_t*)(Xs + lane * 48 + 16) = *(bf16x8_t*)&xr[8];

    // --- layer 1 MFMA: A-frag row=l15 (pos); lg>=2 lanes re-read valid bytes, B=0 there ---
    const int lgm16 = (lg & 1) * 16;
    f32x4_t h1[4][2];
#pragma unroll
    for (int p = 0; p < 4; p++) {
        const bf16x8_t a1 = *(const bf16x8_t*)(Xs + (p * 16 + l15) * 48 + lgm16);
#pragma unroll
        for (int ot = 0; ot < 2; ot++)
            h1[p][ot] = mfma16(a1, b1f[ot], bc1v[ot]);
    }

    // --- GELU (sigmoid form), write H to LDS [64][40bf16] ---
#pragma unroll
    for (int p = 0; p < 4; p++)
#pragma unroll
        for (int ot = 0; ot < 2; ot++)
#pragma unroll
            for (int r = 0; r < 4; r++) {
                const float g = gelu_fast(h1[p][ot][r]);
                *(bf16_t*)(Hs + (p * 16 + lg * 4 + r) * 80 + (ot * 16 + l15) * 2) = (bf16_t)g;
            }

    // --- layer 2 MFMA + direct bf16x4 store (C rows are 4 consecutive k) ---
    const size_t obase = ((size_t)(b * 16 + l15) * 512 + q) * 512 + k0;
#pragma unroll
    for (int p = 0; p < 4; p++) {
        const bf16x8_t a2 = *(const bf16x8_t*)(Hs + (p * 16 + l15) * 80 + lg * 16);
        const f32x4_t o2 = mfma16(a2, b2f, cinit2);
        bf16x4_t ov;
#pragma unroll
        for (int r = 0; r < 4; r++) ov[r] = (bf16_t)o2[r];
        *(bf16x4_t*)&biasb[obase + p * 16 + lg * 4] = ov;
    }
}

// ---------------------------------------------------------------------------
// bf16 GEMM: C[M,N] = A[M,K] @ W[N,K]^T + bias   (m97 structure: 128x128 tile,
// BK=32, global_load_lds staging, 4 waves 2x2, 16x16x32 MFMA)
// Block mapping: XCD-bijective chunking + GM=8 supertile (tm fast, tn slow)
// so each XCD works a contiguous panel region (L2 locality).
// EPI: 0 = f32 out, 1 = bf16 out, 2 = relu -> bf16 out, 3 = QKV fused bf16 out
//      (EPI 3 scales Q columns by 1/sqrt(DH) = 0.125 -- exact pow2 scale)
// SPLIT: blockIdx.y selects K-half; f32 partials at Cf + ks*M*N; bias on ks==0
// ---------------------------------------------------------------------------
template <int EPI, bool SPLIT>
__global__ __launch_bounds__(256)
void gemm_bt(const bf16_t* __restrict__ A, const bf16_t* __restrict__ A2,
             const bf16_t* __restrict__ Bw,
             const float* __restrict__ bias, float* __restrict__ Cf,
             bf16_t* __restrict__ Cb, int M, int N, int Klen, int lda) {
    __shared__ __align__(16) bf16_t As[128 * 32];
    __shared__ __align__(16) bf16_t Bs[128 * 32];
    const int t = threadIdx.x, lane = t & 63, w = t >> 6;
    const int wr = w >> 1, wc = w & 1;
    const int ntn = N >> 7;
    const int nwg = (M >> 7) * ntn;
    const int wg  = xcd_swz((int)blockIdx.x, nwg);
    const int gsz = 8 * ntn;                 // GM=8 supertile
    const int gid = wg / gsz;
    const int rem = wg - gid * gsz;
    const int tm  = gid * 8 + (rem & 7);
    const int tn  = rem >> 3;
    const int l15 = lane & 15, lg = lane >> 4;
    const int ks = SPLIT ? blockIdx.y : 0;
    const int koff = SPLIT ? ks * Klen : 0;
    if (EPI == 3 && tn >= 8) A = A2;   // Q cols use q-input; K/V cols use kv-input

    f32x4_t acc[4][4];
#pragma unroll
    for (int i = 0; i < 4; i++)
#pragma unroll
        for (int j = 0; j < 4; j++) acc[i][j] = f32x4_t{0.f, 0.f, 0.f, 0.f};

    const int nk = Klen >> 5;
    for (int kt = 0; kt < nk; ++kt) {
#pragma unroll
        for (int i = 0; i < 2; i++) {
            const int c = i * 256 + w * 64 + lane;
            const int c0 = i * 256 + w * 64;
            const int row = c >> 2, kg = c & 3;
            gload_lds16(A + (size_t)(tm * 128 + row) * lda + koff + kt * 32 + kg * 8, &As[c0 * 8]);
        }
#pragma unroll
        for (int i = 0; i < 2; i++) {
            const int c = i * 256 + w * 64 + lane;
            const int c0 = i * 256 + w * 64;
            const int row = c >> 2, kg = c & 3;
            gload_lds16(Bw + (size_t)(tn * 128 + row) * lda + koff + kt * 32 + kg * 8, &Bs[c0 * 8]);
        }
        __syncthreads();

        bf16x8_t af[4], bfv[4];
#pragma unroll
        for (int mt = 0; mt < 4; mt++)
            af[mt] = *(const bf16x8_t*)&As[(wr * 64 + mt * 16 + l15) * 32 + lg * 8];
#pragma unroll
        for (int nt = 0; nt < 4; nt++)
            bfv[nt] = *(const bf16x8_t*)&Bs[(wc * 64 + nt * 16 + l15) * 32 + lg * 8];
#pragma unroll
        for (int mt = 0; mt < 4; mt++)
#pragma unroll
            for (int nt = 0; nt < 4; nt++)
                acc[mt][nt] = mfma16(af[mt], bfv[nt], acc[mt][nt]);
        __syncthreads();
    }

#pragma unroll
    for (int nt = 0; nt < 4; nt++) {
        const int col = tn * 128 + wc * 64 + nt * 16 + l15;
        float bv = bias[col];
        if (SPLIT && ks != 0) bv = 0.f;
#pragma unroll
        for (int mt = 0; mt < 4; mt++) {
#pragma unroll
            for (int r = 0; r < 4; r++) {
                const int row = tm * 128 + wr * 64 + mt * 16 + lg * 4 + r;
                float v = acc[mt][nt][r] + bv;
                if (EPI == 2) v = fmaxf(v, 0.f);
                if (EPI == 3 && tn < 8) v *= 0.125f;     // fold 1/sqrt(DH) into Q
                if (EPI == 0) Cf[(size_t)ks * M * N + (size_t)row * N + col] = v;
                else if (EPI == 3)
                    Cb[(size_t)(col >> 10) * 4194304 + (size_t)row * 1024 + (col & 1023)] = (bf16_t)v;
                else Cb[(size_t)row * N + col] = (bf16_t)v;
            }
        }
    }
}

// ---------------------------------------------------------------------------
// Flash attention with additive bias.  One block = (b, h, 64-row q-tile),
// 4 waves; wave w owns q rows [16w,16w+16).  Q/K/V/P LDS tiles XOR-swizzled;
// bias tile staged via registers (uint4 load + ds_write, linear [q][k]).
// Q is pre-scaled by 0.125 at projection time.  XCD-chunked bid.
// ---------------------------------------------------------------------------
__global__ __launch_bounds__(256)
void attn_kernel(const bf16_t* __restrict__ Qp, const bf16_t* __restrict__ Kp,
                 const bf16_t* __restrict__ Vp, const bf16_t* __restrict__ biasb,
                 bf16_t* __restrict__ ctx) {
    __shared__ __align__(16) bf16_t Qs[64 * 64];
    __shared__ __align__(16) bf16_t Ks[64 * 64];
    __shared__ __align__(16) bf16_t Vts[64 * 64];   // V transposed: Vts[d][k]
    __shared__ __align__(16) bf16_t Ps[64 * 64];
    __shared__ __align__(16) bf16_t Bbs[64 * 64];   // bias tile, linear [q][k]

    const int bid = xcd_swz((int)blockIdx.x, 1024);
    const int qt = bid & 7, h = (bid >> 3) & 15, b = bid >> 7;
    const int t = threadIdx.x, lane = t & 63, w = t >> 6;
    const int l15 = lane & 15, lg = lane >> 4;

    // stage Q tile (swizzled)
#pragma unroll
    for (int i = 0; i < 2; i++) {
        const int c = t + i * 256;
        const int row = c >> 3, cg = c & 7;
        const uint4 v = *(const uint4*)&Qp[(((size_t)(b * LQ_ + qt * 64 + row)) * H_ + h) * DH_ + cg * 8];
        *(uint4*)((char*)Qs + row * 128 + ((cg ^ (row & 7)) << 4)) = v;
    }

    f32x4_t oacc[4];
#pragma unroll
    for (int i = 0; i < 4; i++) oacc[i] = f32x4_t{0.f, 0.f, 0.f, 0.f};
    float mrow[4] = {-1e30f, -1e30f, -1e30f, -1e30f};
    float lrow[4] = {0.f, 0.f, 0.f, 0.f};

    const bf16_t* bias_tile = biasb + ((size_t)(b * H_ + h) * LQ_ + qt * 64) * LKV_;

    for (int kt = 0; kt < 8; ++kt) {
        __syncthreads();   // previous iteration done with Ks/Vts/Bbs
#pragma unroll
        for (int i = 0; i < 2; i++) {
            const int c = t + i * 256;
            const int row = c >> 3, cg = c & 7;
            const uint4 v = *(const uint4*)&Kp[(((size_t)(b * LKV_ + kt * 64 + row)) * H_ + h) * DH_ + cg * 8];
            *(uint4*)((char*)Ks + row * 128 + ((cg ^ (row & 7)) << 4)) = v;
        }
        // stage bias tile via registers (coalesced 16B, linear LDS [q][k])
#pragma unroll
        for (int i = 0; i < 2; i++) {
            const int c = t + i * 256;
            const int row = c >> 3, cg = c & 7;
            const uint4 bv4 = *(const uint4*)&bias_tile[(size_t)row * LKV_ + kt * 64 + cg * 8];
            *(uint4*)&Bbs[row * 64 + cg * 8] = bv4;
        }
#pragma unroll
        for (int i = 0; i < 2; i++) {
            const int c = t + i * 256;
            const int k = c >> 3, dg = c & 7;
            const bf16x8_t vv = *(const bf16x8_t*)&Vp[(((size_t)(b * LKV_ + kt * 64 + k)) * H_ + h) * DH_ + dg * 8];
#pragma unroll
            for (int j = 0; j < 8; j++) {
                const int d = dg * 8 + j;
                *(bf16_t*)((char*)Vts + d * 128 + ((((k * 2) >> 4) ^ (d & 7)) << 4) + ((k * 2) & 15)) = vv[j];
            }
        }
        __syncthreads();

        // S = Q K^T
        f32x4_t sacc[4];
#pragma unroll
        for (int i = 0; i < 4; i++) sacc[i] = f32x4_t{0.f, 0.f, 0.f, 0.f};
        bf16x8_t aq[2];
        {
            const int rowq = w * 16 + l15;
#pragma unroll
            for (int kc = 0; kc < 2; kc++)
                aq[kc] = *(const bf16x8_t*)((const char*)Qs + rowq * 128 + (((kc * 4 + lg) ^ (rowq & 7)) << 4));
        }
#pragma unroll
        for (int nt = 0; nt < 4; nt++) {
            const int rowk = nt * 16 + l15;
#pragma unroll
            for (int kc = 0; kc < 2; kc++) {
                const bf16x8_t bk = *(const bf16x8_t*)((const char*)Ks + rowk * 128 + (((kc * 4 + lg) ^ (rowk & 7)) << 4));
                sacc[nt] = mfma16(aq[kc], bk, sacc[nt]);
            }
        }

        // bias add + online softmax.  D-layout: row = 4*lg + r, col = 16*nt + l15
        float esc[4];
#pragma unroll
        for (int r = 0; r < 4; r++) {
            const int qr = w * 16 + lg * 4 + r;
            float mx = -1e30f;
#pragma unroll
            for (int nt = 0; nt < 4; nt++) {
                const float bvv = (float)Bbs[qr * 64 + nt * 16 + l15];
                const float v = sacc[nt][r] + bvv;
                sacc[nt][r] = v;
                mx = fmaxf(mx, v);
            }
#pragma unroll
            for (int msk = 8; msk >= 1; msk >>= 1) mx = fmaxf(mx, __shfl_xor(mx, msk));
            const float mnew = fmaxf(mrow[r], mx);
            esc[r] = __expf(mrow[r] - mnew);
            mrow[r] = mnew;
            float rs = 0.f;
#pragma unroll
            for (int nt = 0; nt < 4; nt++) {
                const float p = __expf(sacc[nt][r] - mnew);
                sacc[nt][r] = p;
                rs += p;
            }
#pragma unroll
            for (int msk = 8; msk >= 1; msk >>= 1) rs += __shfl_xor(rs, msk);
            lrow[r] = lrow[r] * esc[r] + rs;
        }

        // write P (bf16) into own wave strip of Ps
#pragma unroll
        for (int r = 0; r < 4; r++) {
            const int prow = w * 16 + lg * 4 + r;
#pragma unroll
            for (int nt = 0; nt < 4; nt++) {
                const int pc2 = (nt * 16 + l15) * 2;
                *(bf16_t*)((char*)Ps + prow * 128 + (((pc2 >> 4) ^ (prow & 7)) << 4) + (pc2 & 15)) =
                    (bf16_t)sacc[nt][r];
            }
        }
        asm volatile("s_waitcnt lgkmcnt(0)" ::: "memory");
        __builtin_amdgcn_sched_barrier(0);

        // rescale O then accumulate P @ V
#pragma unroll
        for (int dt = 0; dt < 4; dt++)
#pragma unroll
            for (int r = 0; r < 4; r++) oacc[dt][r] *= esc[r];

        bf16x8_t pa[2];
        {
            const int rowp = w * 16 + l15;
#pragma unroll
            for (int kc = 0; kc < 2; kc++)
                pa[kc] = *(const bf16x8_t*)((const char*)Ps + rowp * 128 + (((kc * 4 + lg) ^ (rowp & 7)) << 4));
        }
#pragma unroll
        for (int dt = 0; dt < 4; dt++) {
            const int rowv = dt * 16 + l15;
#pragma unroll
            for (int kc = 0; kc < 2; kc++) {
                const bf16x8_t bv = *(const bf16x8_t*)((const char*)Vts + rowv * 128 + (((kc * 4 + lg) ^ (rowv & 7)) << 4));
                oacc[dt] = mfma16(pa[kc], bv, oacc[dt]);
            }
        }
    }

    float inv[4];
#pragma unroll
    for (int r = 0; r < 4; r++) inv[r] = __builtin_amdgcn_rcpf(lrow[r]);
#pragma unroll
    for (int dt = 0; dt < 4; dt++) {
#pragma unroll
        for (int r = 0; r < 4; r++) {
            const float v = oacc[dt][r] * inv[r];
            const int q = qt * 64 + w * 16 + lg * 4 + r;
            const int d = dt * 16 + l15;
            ctx[(((size_t)(b * LQ_ + q)) * H_ + h) * DH_ + d] = (bf16_t)v;
        }
    }
}

// ---------------------------------------------------------------------------
// out = LayerNorm(X + Y0 + Y1) * g + b ; optional bf16 copy.  One block per row.
// ---------------------------------------------------------------------------
__global__ __launch_bounds__(256)
void add_ln3_kernel(const float* __restrict__ X, const float* __restrict__ Y0,
                    const float* __restrict__ Y1,
                    const float* __restrict__ g, const float* __restrict__ be,
                    float* __restrict__ of, bf16_t* __restrict__ ob) {
    const int row = blockIdx.x, t = threadIdx.x;
    const float4 xv = ((const float4*)(X + (size_t)row * 1024))[t];
    const float4 y0 = ((const float4*)(Y0 + (size_t)row * 1024))[t];
    const float4 y1 = ((const float4*)(Y1 + (size_t)row * 1024))[t];
    float v[4] = {xv.x + y0.x + y1.x, xv.y + y0.y + y1.y,
                  xv.z + y0.z + y1.z, xv.w + y0.w + y1.w};
    float s = v[0] + v[1] + v[2] + v[3];
    float s2 = v[0] * v[0] + v[1] * v[1] + v[2] * v[2] + v[3] * v[3];
#pragma unroll
    for (int m = 32; m >= 1; m >>= 1) { s += __shfl_xor(s, m); s2 += __shfl_xor(s2, m); }
    __shared__ float red[8];
    const int w = t >> 6, lane = t & 63;
    if (lane == 0) { red[w] = s; red[4 + w] = s2; }
    __syncthreads();
    s = red[0] + red[1] + red[2] + red[3];
    s2 = red[4] + red[5] + red[6] + red[7];
    const float mu = s * (1.f / 1024.f);
    const float var = s2 * (1.f / 1024.f) - mu * mu;
    const float rstd = rsqrtf(var + 1e-6f);
    const float4 gv = ((const float4*)g)[t];
    const float4 bv = ((const float4*)be)[t];
    float o[4];
    o[0] = (v[0] - mu) * rstd * gv.x + bv.x;
    o[1] = (v[1] - mu) * rstd * gv.y + bv.y;
    o[2] = (v[2] - mu) * rstd * gv.z + bv.z;
    o[3] = (v[3] - mu) * rstd * gv.w + bv.w;
    ((float4*)(of + (size_t)row * 1024))[t] = make_float4(o[0], o[1], o[2], o[3]);
    if (ob) {
        bf16x4_t qo;
        qo[0] = (bf16_t)o[0]; qo[1] = (bf16_t)o[1]; qo[2] = (bf16_t)o[2]; qo[3] = (bf16_t)o[3];
        ((bf16x4_t*)(ob + (size_t)row * 1024))[t] = qo;
    }
}

// ---------------------------------------------------------------------------
extern "C" void kernel_launch(void* const* d_in, const int* in_sizes, int n_in,
                              void* d_out, int out_size, void* d_ws, size_t ws_size,
                              hipStream_t stream) {
    (void)in_sizes; (void)n_in; (void)out_size; (void)ws_size;
    const float* q    = (const float*)d_in[0];
    const float* kv   = (const float*)d_in[1];
    const float* amap = (const float*)d_in[2];
    const float* Wq = (const float*)d_in[3];  const float* bQ = (const float*)d_in[4];
    const float* Wk = (const float*)d_in[5];  const float* bK = (const float*)d_in[6];
    const float* Wv = (const float*)d_in[7];  const float* bV = (const float*)d_in[8];
    const float* Wm = (const float*)d_in[9];  const float* bM = (const float*)d_in[10];
    const float* Wc1 = (const float*)d_in[11]; const float* bc1 = (const float*)d_in[12];
    const float* Wc2 = (const float*)d_in[13]; const float* bc2 = (const float*)d_in[14];
    const float* Wf1 = (const float*)d_in[15]; const float* bf1 = (const float*)d_in[16];
    const float* Wf2 = (const float*)d_in[17]; const float* bf2 = (const float*)d_in[18];
    const float* g1 = (const float*)d_in[19]; const float* b1 = (const float*)d_in[20];
    const float* g2 = (const float*)d_in[21]; const float* b2 = (const float*)d_in[22];

    char* w = (char*)d_ws;
    // region [0, 67108864): biasb; later p0/p1; later hb + f0/f1
    bf16_t* biasb = (bf16_t*)(w);
    float*  p0    = (float*)(w);                    // 16 MB (after attn)
    float*  p1    = (float*)(w + 16777216);         // 16 MB
    bf16_t* hb    = (bf16_t*)(w);                   // 32 MB (after add_ln3 #1)
    float*  f0    = (float*)(w + 33554432);         // 16 MB
    float*  f1    = (float*)(w + 50331648);         // 16 MB
    bf16_t* qb   = (bf16_t*)(w + 67108864);         // 8 MB ; ctx after QKV
    bf16_t* kvb  = (bf16_t*)(w + 75497472);         // 8 MB
    bf16_t* Qp   = (bf16_t*)(w + 83886080);         // 8 MB each, Q|K|V contiguous
    bf16_t* Kp   = (bf16_t*)(w + 92274688);
    bf16_t* Vp   = (bf16_t*)(w + 100663296);
    bf16_t* Wqkvb = (bf16_t*)(w + 109051904);       // 6 MB (Wq|Wk|Wv bf16)
    bf16_t* Wmb  = (bf16_t*)(w + 115343360);        // 2 MB
    bf16_t* Wf1b = (bf16_t*)(w + 117440512);        // 8 MB
    bf16_t* Wf2b = (bf16_t*)(w + 125829120);        // 8 MB
    float*  bqkv = (float*)(w + 134217728);         // 12 KB
    bf16_t* ctx = qb;                               // qb dead after QKV gemm
    float*  xf  = (float*)Qp;                       // 16 MB over Qp+Kp (dead after attn)
    bf16_t* xb  = Vp;                               // Vp dead after attn

    dim3 blk(256);
    cvt_bf16_kernel<<<4096, blk, 0, stream>>>(q,   qb,   1048576);
    cvt_bf16_kernel<<<4096, blk, 0, stream>>>(kv,  kvb,  1048576);
    cvt_bf16_kernel<<<1024, blk, 0, stream>>>(Wq,  Wqkvb,           262144);
    cvt_bf16_kernel<<<1024, blk, 0, stream>>>(Wk,  Wqkvb + 1048576, 262144);
    cvt_bf16_kernel<<<1024, blk, 0, stream>>>(Wv,  Wqkvb + 2097152, 262144);
    cvt_bf16_kernel<<<1024, blk, 0, stream>>>(Wm,  Wmb,  262144);
    cvt_bf16_kernel<<<4096, blk, 0, stream>>>(Wf1, Wf1b, 1048576);
    cvt_bf16_kernel<<<4096, blk, 0, stream>>>(Wf2, Wf2b, 1048576);
    pack3_kernel<<<4, blk, 0, stream>>>(bQ, bK, bV, bqkv);

    bias_mlp_mfma<<<8192, blk, 0, stream>>>(amap, Wc1, bc1, Wc2, bc2, biasb);

    // fused QKV projection: N=3072, A chosen per column block (q for cols<1024)
    gemm_bt<3, false><<<768, blk, 0, stream>>>(qb, kvb, Wqkvb, bqkv, nullptr, Qp,
                                               4096, 3072, 1024, 1024);

    attn_kernel<<<1024, blk, 0, stream>>>(Qp, Kp, Vp, biasb, ctx);

    // out-proj, split-K=2 -> p0,p1 (overwrites biasb region, dead now)
    gemm_bt<0, true><<<dim3(256, 2), blk, 0, stream>>>(ctx, nullptr, Wmb, bM, p0, nullptr,
                                                       4096, 1024, 512, 1024);
    add_ln3_kernel<<<4096, blk, 0, stream>>>(q, p0, p1, g1, b1, xf, xb);

    // FFN1 (relu, bf16) -> hb
    gemm_bt<2, false><<<1024, blk, 0, stream>>>(xb, nullptr, Wf1b, bf1, nullptr, hb,
                                                4096, 4096, 1024, 1024);
    // FFN2, split-K=2 -> f0,f1
    gemm_bt<0, true><<<dim3(256, 2), blk, 0, stream>>>(hb, nullptr, Wf2b, bf2, f0, nullptr,
                                                       4096, 1024, 2048, 4096);
    add_ln3_kernel<<<4096, blk, 0, stream>>>(xf, f0, f1, g2, b2, (float*)d_out, nullptr);
}

// Round 7
// 332.819 us; speedup vs baseline: 1.5802x; 1.0941x over previous
//
#include <hip/hip_runtime.h>
#include <hip/hip_bf16.h>

typedef __bf16 bf16_t;
typedef __bf16 bf16x4_t __attribute__((ext_vector_type(4)));
typedef __bf16 bf16x8_t __attribute__((ext_vector_type(8)));
typedef float  f32x4_t  __attribute__((ext_vector_type(4)));

#define B_   8
#define LQ_  512
#define LKV_ 512
#define D_   1024
#define H_   16
#define DH_  64
#define FF_  4096

__device__ __forceinline__ f32x4_t mfma16(bf16x8_t a, bf16x8_t b, f32x4_t c) {
    return __builtin_amdgcn_mfma_f32_16x16x32_bf16(a, b, c, 0, 0, 0);
}

__device__ __forceinline__ void gload_lds16(const bf16_t* g, bf16_t* l) {
    __builtin_amdgcn_global_load_lds(
        (const __attribute__((address_space(1))) void*)g,
        (__attribute__((address_space(3))) void*)l, 16, 0, 0);
}

// bijective XCD chunking: blocks with pid%8==x (same XCD, HW round-robin)
// get a CONTIGUOUS range of work indices.  Requires nwg % 8 == 0.
__device__ __forceinline__ int xcd_swz(int pid, int nwg) {
    return (pid & 7) * (nwg >> 3) + (pid >> 3);
}

// fast GELU: h * sigmoid(1.702 h).  |err| <= ~0.02 absolute -> ~0.002 on the
// attn logits after W2 (rms 0.02, 32 terms) -- far under the 0.1 threshold.
__device__ __forceinline__ float gelu_fast(float h) {
    const float e = exp2f(h * -2.45546696f);     // exp(-1.702 h)
    return h * __builtin_amdgcn_rcpf(1.f + e);
}

// ---------------------------------------------------------------------------
// fused f32 -> bf16 convert for all 8 tensors (one launch).
// dst regions are 3 contiguous ws ranges: [qb|kvb], [Wq|Wk|Wv|Wm], [Wf1|Wf2].
// ---------------------------------------------------------------------------
__global__ __launch_bounds__(256)
void cvt_all_kernel(const float* __restrict__ q,  const float* __restrict__ kv,
                    const float* __restrict__ Wq, const float* __restrict__ Wk,
                    const float* __restrict__ Wv, const float* __restrict__ Wm,
                    const float* __restrict__ Wf1,const float* __restrict__ Wf2,
                    bf16_t* __restrict__ dq, bf16_t* __restrict__ dW,
                    bf16_t* __restrict__ dF) {
    const int i = blockIdx.x * 256 + threadIdx.x;    // grid 20480 -> i < 5242880
    const float* s; bf16_t* d; int j;
    if (i < 1048576)      { s = q;   d = dq;           j = i; }
    else if (i < 2097152) { s = kv;  d = dq + 4194304; j = i - 1048576; }
    else if (i < 2359296) { s = Wq;  d = dW;           j = i - 2097152; }
    else if (i < 2621440) { s = Wk;  d = dW + 1048576; j = i - 2359296; }
    else if (i < 2883584) { s = Wv;  d = dW + 2097152; j = i - 2621440; }
    else if (i < 3145728) { s = Wm;  d = dW + 3145728; j = i - 2883584; }
    else if (i < 4194304) { s = Wf1; d = dF;           j = i - 3145728; }
    else                  { s = Wf2; d = dF + 4194304; j = i - 4194304; }
    const float4 v = ((const float4*)s)[j];
    bf16x4_t o;
    o[0] = (bf16_t)v.x; o[1] = (bf16_t)v.y; o[2] = (bf16_t)v.z; o[3] = (bf16_t)v.w;
    ((bf16x4_t*)d)[j] = o;
}

__global__ __launch_bounds__(256)
void pack3_kernel(const float* __restrict__ a, const float* __restrict__ b,
                  const float* __restrict__ c, float* __restrict__ o) {
    const int i = blockIdx.x * 256 + threadIdx.x;   // grid 4 -> i < 1024
    o[i] = a[i]; o[1024 + i] = b[i]; o[2048 + i] = c[i];
}

// ---------------------------------------------------------------------------
// AttentionBiasMLP via MFMA.  One wave handles 64 consecutive positions
// (same b,q; k = k0..k0+63).  Wave-private LDS; no block barriers.
// W1 is prescaled by ln2 so inputs use raw log2.
// ---------------------------------------------------------------------------
__global__ __launch_bounds__(256)
void bias_mlp_mfma(const float* __restrict__ amap,
                   const float* __restrict__ Wc1, const float* __restrict__ bc1,
                   const float* __restrict__ Wc2, const float* __restrict__ bc2,
                   bf16_t* __restrict__ biasb) {
    __shared__ __align__(16) char lds[4][8192];  // per wave: Xs [0,3072) rows 48B; Hs [3072,8192) rows 80B
    const int t = threadIdx.x, lane = t & 63, w = t >> 6;
    const int l15 = lane & 15, lg = lane >> 4;
    char* Xs = lds[w];
    char* Hs = lds[w] + 3072;

    // --- weight fragments (registers, once).  W1 *= ln2 (log2 input fold) ---
    bf16x8_t b1f[2], b2f;
    f32x4_t bc1v[2];
#pragma unroll
    for (int ot = 0; ot < 2; ot++) {
        bf16x8_t v;
#pragma unroll
        for (int i = 0; i < 8; i++) {
            const int kk = (lg * 8 + i) & 15;                       // in-bounds always
            const float wv = Wc1[(ot * 16 + l15) * 16 + kk] * 0.69314718055994531f;
            v[i] = (lg < 2) ? (bf16_t)wv : (bf16_t)0.f;             // zero-pad K 16->32
        }
        b1f[ot] = v;
        const float bb = bc1[ot * 16 + l15];
        bc1v[ot] = f32x4_t{bb, bb, bb, bb};
    }
    {
        bf16x8_t v;
#pragma unroll
        for (int i = 0; i < 8; i++) v[i] = (bf16_t)Wc2[l15 * 32 + lg * 8 + i];
        b2f = v;
    }
    const float bc2s = bc2[l15];
    const f32x4_t cinit2 = f32x4_t{bc2s, bc2s, bc2s, bc2s};

    // --- positions ---
    const int posb = (blockIdx.x * 4 + w) * 64;
    const int b  = posb >> 18;
    const int q  = (posb >> 9) & 511;
    const int k0 = posb & 511;

    // --- load 16 channels, log2, stage to LDS (row = lane, 16 bf16, stride 48B) ---
    const float* src = amap + (size_t)(b * 16) * 263169 + (size_t)(q + 1) * 513 + (k0 + 1 + lane);
    bf16_t xr[16];
#pragma unroll
    for (int c = 0; c < 16; c++) {
        const float v = src[(size_t)c * 263169];
        xr[c] = (bf16_t)__log2f(v + 1e-6f);
    }
    *(bf16x8_t*)(Xs + lane * 48)      = *(bf16x8_t*)&xr[0];
    *(bf16x8_t*)(Xs + lane * 48 + 16) = *(bf16x8_t*)&xr[8];

    // --- layer 1 MFMA: A-frag row=l15 (pos); lg>=2 lanes re-read valid bytes, B=0 there ---
    const int lgm16 = (lg & 1) * 16;
    f32x4_t h1[4][2];
#pragma unroll
    for (int p = 0; p < 4; p++) {
        const bf16x8_t a1 = *(const bf16x8_t*)(Xs + (p * 16 + l15) * 48 + lgm16);
#pragma unroll
        for (int ot = 0; ot < 2; ot++)
            h1[p][ot] = mfma16(a1, b1f[ot], bc1v[ot]);
    }

    // --- GELU (sigmoid form), write H to LDS [64][40bf16] ---
#pragma unroll
    for (int p = 0; p < 4; p++)
#pragma unroll
        for (int ot = 0; ot < 2; ot++)
#pragma unroll
            for (int r = 0; r < 4; r++) {
                const float g = gelu_fast(h1[p][ot][r]);
                *(bf16_t*)(Hs + (p * 16 + lg * 4 + r) * 80 + (ot * 16 + l15) * 2) = (bf16_t)g;
            }

    // --- layer 2 MFMA + direct bf16x4 store (C rows are 4 consecutive k) ---
    const size_t obase = ((size_t)(b * 16 + l15) * 512 + q) * 512 + k0;
#pragma unroll
    for (int p = 0; p < 4; p++) {
        const bf16x8_t a2 = *(const bf16x8_t*)(Hs + (p * 16 + l15) * 80 + lg * 16);
        const f32x4_t o2 = mfma16(a2, b2f, cinit2);
        bf16x4_t ov;
#pragma unroll
        for (int r = 0; r < 4; r++) ov[r] = (bf16_t)o2[r];
        *(bf16x4_t*)&biasb[obase + p * 16 + lg * 4] = ov;
    }
}

// ---------------------------------------------------------------------------
// bf16 GEMM: C[M,N] = A[M,K] @ W[N,K]^T + bias.  128x128 tile, BK=32,
// DOUBLE-BUFFERED global_load_lds staging (T3 2-phase: stage k+1 overlaps
// MFMA on k; ONE vmcnt(0)+barrier per K-step).  4 waves 2x2, 16x16x32 MFMA.
// Block mapping: XCD-bijective chunking + GM=8 supertile (L2 locality).
// EPI: 0 = f32 out, 1 = bf16 out, 2 = relu -> bf16 out, 3 = QKV fused bf16 out
//      (EPI 3 scales Q columns by 1/sqrt(DH) = 0.125 -- exact pow2 scale)
// SPLIT: blockIdx.y selects K-half; f32 partials at Cf + ks*M*N; bias on ks==0
// ---------------------------------------------------------------------------
template <int EPI, bool SPLIT>
__global__ __launch_bounds__(256)
void gemm_bt(const bf16_t* __restrict__ A, const bf16_t* __restrict__ A2,
             const bf16_t* __restrict__ Bw,
             const float* __restrict__ bias, float* __restrict__ Cf,
             bf16_t* __restrict__ Cb, int M, int N, int Klen, int lda) {
    __shared__ __align__(16) bf16_t As[2][128 * 32];
    __shared__ __align__(16) bf16_t Bs[2][128 * 32];
    const int t = threadIdx.x, lane = t & 63, w = t >> 6;
    const int wr = w >> 1, wc = w & 1;
    const int ntn = N >> 7;
    const int nwg = (M >> 7) * ntn;
    const int wg  = xcd_swz((int)blockIdx.x, nwg);
    const int gsz = 8 * ntn;                 // GM=8 supertile
    const int gid = wg / gsz;
    const int rem = wg - gid * gsz;
    const int tm  = gid * 8 + (rem & 7);
    const int tn  = rem >> 3;
    const int l15 = lane & 15, lg = lane >> 4;
    const int ks = SPLIT ? blockIdx.y : 0;
    const int koff = SPLIT ? ks * Klen : 0;
    if (EPI == 3 && tn >= 8) A = A2;   // Q cols use q-input; K/V cols use kv-input

    // per-thread staging coordinates (c = i*256 + w*64 + lane)
    const int c0_ = t;            // i=0 chunk
    const int c1_ = t + 256;      // i=1 chunk
    const int r0 = c0_ >> 2, k0 = c0_ & 3;
    const int r1 = c1_ >> 2, k1 = c1_ & 3;
    const int b0 = (w * 64) * 8;             // LDS elem base, i=0
    const int b1 = (256 + w * 64) * 8;       // LDS elem base, i=1
    const bf16_t* Abase0 = A  + (size_t)(tm * 128 + r0) * lda + koff + k0 * 8;
    const bf16_t* Abase1 = A  + (size_t)(tm * 128 + r1) * lda + koff + k1 * 8;
    const bf16_t* Bbase0 = Bw + (size_t)(tn * 128 + r0) * lda + koff + k0 * 8;
    const bf16_t* Bbase1 = Bw + (size_t)(tn * 128 + r1) * lda + koff + k1 * 8;

    f32x4_t acc[4][4];
#pragma unroll
    for (int i = 0; i < 4; i++)
#pragma unroll
        for (int j = 0; j < 4; j++) acc[i][j] = f32x4_t{0.f, 0.f, 0.f, 0.f};

    const int nk = Klen >> 5;

    // prologue: stage tile 0 into buffer 0
    gload_lds16(Abase0, &As[0][b0]);
    gload_lds16(Abase1, &As[0][b1]);
    gload_lds16(Bbase0, &Bs[0][b0]);
    gload_lds16(Bbase1, &Bs[0][b1]);
    asm volatile("s_waitcnt vmcnt(0)" ::: "memory");
    __syncthreads();

    int cur = 0;
    for (int kt = 0; kt < nk; ++kt) {
        // stage next tile into the other buffer (overlaps MFMA below)
        if (kt + 1 < nk) {
            const int ko = (kt + 1) * 32;
            gload_lds16(Abase0 + ko, &As[cur ^ 1][b0]);
            gload_lds16(Abase1 + ko, &As[cur ^ 1][b1]);
            gload_lds16(Bbase0 + ko, &Bs[cur ^ 1][b0]);
            gload_lds16(Bbase1 + ko, &Bs[cur ^ 1][b1]);
        }

        const bf16_t* Ac = As[cur];
        const bf16_t* Bc = Bs[cur];
        bf16x8_t af[4], bfv[4];
#pragma unroll
        for (int mt = 0; mt < 4; mt++)
            af[mt] = *(const bf16x8_t*)&Ac[(wr * 64 + mt * 16 + l15) * 32 + lg * 8];
#pragma unroll
        for (int nt = 0; nt < 4; nt++)
            bfv[nt] = *(const bf16x8_t*)&Bc[(wc * 64 + nt * 16 + l15) * 32 + lg * 8];
#pragma unroll
        for (int mt = 0; mt < 4; mt++)
#pragma unroll
            for (int nt = 0; nt < 4; nt++)
                acc[mt][nt] = mfma16(af[mt], bfv[nt], acc[mt][nt]);

        if (kt + 1 < nk) {
            asm volatile("s_waitcnt vmcnt(0)" ::: "memory");
            __syncthreads();
            cur ^= 1;
        }
    }

#pragma unroll
    for (int nt = 0; nt < 4; nt++) {
        const int col = tn * 128 + wc * 64 + nt * 16 + l15;
        float bv = bias[col];
        if (SPLIT && ks != 0) bv = 0.f;
#pragma unroll
        for (int mt = 0; mt < 4; mt++) {
#pragma unroll
            for (int r = 0; r < 4; r++) {
                const int row = tm * 128 + wr * 64 + mt * 16 + lg * 4 + r;
                float v = acc[mt][nt][r] + bv;
                if (EPI == 2) v = fmaxf(v, 0.f);
                if (EPI == 3 && tn < 8) v *= 0.125f;     // fold 1/sqrt(DH) into Q
                if (EPI == 0) Cf[(size_t)ks * M * N + (size_t)row * N + col] = v;
                else if (EPI == 3)
                    Cb[(size_t)(col >> 10) * 4194304 + (size_t)row * 1024 + (col & 1023)] = (bf16_t)v;
                else Cb[(size_t)row * N + col] = (bf16_t)v;
            }
        }
    }
}

// ---------------------------------------------------------------------------
// Flash attention with additive bias.  One block = (b, h, 64-row q-tile),
// 4 waves; wave w owns q rows [16w,16w+16).  Q/K/V/P LDS tiles XOR-swizzled;
// bias tile staged via registers (uint4 load + ds_write, linear [q][k]).
// Q is pre-scaled by 0.125 at projection time.  XCD-chunked bid.
// ---------------------------------------------------------------------------
__global__ __launch_bounds__(256)
void attn_kernel(const bf16_t* __restrict__ Qp, const bf16_t* __restrict__ Kp,
                 const bf16_t* __restrict__ Vp, const bf16_t* __restrict__ biasb,
                 bf16_t* __restrict__ ctx) {
    __shared__ __align__(16) bf16_t Qs[64 * 64];
    __shared__ __align__(16) bf16_t Ks[64 * 64];
    __shared__ __align__(16) bf16_t Vts[64 * 64];   // V transposed: Vts[d][k]
    __shared__ __align__(16) bf16_t Ps[64 * 64];
    __shared__ __align__(16) bf16_t Bbs[64 * 64];   // bias tile, linear [q][k]

    const int bid = xcd_swz((int)blockIdx.x, 1024);
    const int qt = bid & 7, h = (bid >> 3) & 15, b = bid >> 7;
    const int t = threadIdx.x, lane = t & 63, w = t >> 6;
    const int l15 = lane & 15, lg = lane >> 4;

    // stage Q tile (swizzled)
#pragma unroll
    for (int i = 0; i < 2; i++) {
        const int c = t + i * 256;
        const int row = c >> 3, cg = c & 7;
        const uint4 v = *(const uint4*)&Qp[(((size_t)(b * LQ_ + qt * 64 + row)) * H_ + h) * DH_ + cg * 8];
        *(uint4*)((char*)Qs + row * 128 + ((cg ^ (row & 7)) << 4)) = v;
    }

    f32x4_t oacc[4];
#pragma unroll
    for (int i = 0; i < 4; i++) oacc[i] = f32x4_t{0.f, 0.f, 0.f, 0.f};
    float mrow[4] = {-1e30f, -1e30f, -1e30f, -1e30f};
    float lrow[4] = {0.f, 0.f, 0.f, 0.f};

    const bf16_t* bias_tile = biasb + ((size_t)(b * H_ + h) * LQ_ + qt * 64) * LKV_;

    for (int kt = 0; kt < 8; ++kt) {
        __syncthreads();   // previous iteration done with Ks/Vts/Bbs
#pragma unroll
        for (int i = 0; i < 2; i++) {
            const int c = t + i * 256;
            const int row = c >> 3, cg = c & 7;
            const uint4 v = *(const uint4*)&Kp[(((size_t)(b * LKV_ + kt * 64 + row)) * H_ + h) * DH_ + cg * 8];
            *(uint4*)((char*)Ks + row * 128 + ((cg ^ (row & 7)) << 4)) = v;
        }
        // stage bias tile via registers (coalesced 16B, linear LDS [q][k])
#pragma unroll
        for (int i = 0; i < 2; i++) {
            const int c = t + i * 256;
            const int row = c >> 3, cg = c & 7;
            const uint4 bv4 = *(const uint4*)&bias_tile[(size_t)row * LKV_ + kt * 64 + cg * 8];
            *(uint4*)&Bbs[row * 64 + cg * 8] = bv4;
        }
#pragma unroll
        for (int i = 0; i < 2; i++) {
            const int c = t + i * 256;
            const int k = c >> 3, dg = c & 7;
            const bf16x8_t vv = *(const bf16x8_t*)&Vp[(((size_t)(b * LKV_ + kt * 64 + k)) * H_ + h) * DH_ + dg * 8];
#pragma unroll
            for (int j = 0; j < 8; j++) {
                const int d = dg * 8 + j;
                *(bf16_t*)((char*)Vts + d * 128 + ((((k * 2) >> 4) ^ (d & 7)) << 4) + ((k * 2) & 15)) = vv[j];
            }
        }
        __syncthreads();

        // S = Q K^T
        f32x4_t sacc[4];
#pragma unroll
        for (int i = 0; i < 4; i++) sacc[i] = f32x4_t{0.f, 0.f, 0.f, 0.f};
        bf16x8_t aq[2];
        {
            const int rowq = w * 16 + l15;
#pragma unroll
            for (int kc = 0; kc < 2; kc++)
                aq[kc] = *(const bf16x8_t*)((const char*)Qs + rowq * 128 + (((kc * 4 + lg) ^ (rowq & 7)) << 4));
        }
#pragma unroll
        for (int nt = 0; nt < 4; nt++) {
            const int rowk = nt * 16 + l15;
#pragma unroll
            for (int kc = 0; kc < 2; kc++) {
                const bf16x8_t bk = *(const bf16x8_t*)((const char*)Ks + rowk * 128 + (((kc * 4 + lg) ^ (rowk & 7)) << 4));
                sacc[nt] = mfma16(aq[kc], bk, sacc[nt]);
            }
        }

        // bias add + online softmax.  D-layout: row = 4*lg + r, col = 16*nt + l15
        float esc[4];
#pragma unroll
        for (int r = 0; r < 4; r++) {
            const int qr = w * 16 + lg * 4 + r;
            float mx = -1e30f;
#pragma unroll
            for (int nt = 0; nt < 4; nt++) {
                const float bvv = (float)Bbs[qr * 64 + nt * 16 + l15];
                const float v = sacc[nt][r] + bvv;
                sacc[nt][r] = v;
                mx = fmaxf(mx, v);
            }
#pragma unroll
            for (int msk = 8; msk >= 1; msk >>= 1) mx = fmaxf(mx, __shfl_xor(mx, msk));
            const float mnew = fmaxf(mrow[r], mx);
            esc[r] = __expf(mrow[r] - mnew);
            mrow[r] = mnew;
            float rs = 0.f;
#pragma unroll
            for (int nt = 0; nt < 4; nt++) {
                const float p = __expf(sacc[nt][r] - mnew);
                sacc[nt][r] = p;
                rs += p;
            }
#pragma unroll
            for (int msk = 8; msk >= 1; msk >>= 1) rs += __shfl_xor(rs, msk);
            lrow[r] = lrow[r] * esc[r] + rs;
        }

        // write P (bf16) into own wave strip of Ps
#pragma unroll
        for (int r = 0; r < 4; r++) {
            const int prow = w * 16 + lg * 4 + r;
#pragma unroll
            for (int nt = 0; nt < 4; nt++) {
                const int pc2 = (nt * 16 + l15) * 2;
                *(bf16_t*)((char*)Ps + prow * 128 + (((pc2 >> 4) ^ (prow & 7)) << 4) + (pc2 & 15)) =
                    (bf16_t)sacc[nt][r];
            }
        }
        asm volatile("s_waitcnt lgkmcnt(0)" ::: "memory");
        __builtin_amdgcn_sched_barrier(0);

        // rescale O then accumulate P @ V
#pragma unroll
        for (int dt = 0; dt < 4; dt++)
#pragma unroll
            for (int r = 0; r < 4; r++) oacc[dt][r] *= esc[r];

        bf16x8_t pa[2];
        {
            const int rowp = w * 16 + l15;
#pragma unroll
            for (int kc = 0; kc < 2; kc++)
                pa[kc] = *(const bf16x8_t*)((const char*)Ps + rowp * 128 + (((kc * 4 + lg) ^ (rowp & 7)) << 4));
        }
#pragma unroll
        for (int dt = 0; dt < 4; dt++) {
            const int rowv = dt * 16 + l15;
#pragma unroll
            for (int kc = 0; kc < 2; kc++) {
                const bf16x8_t bv = *(const bf16x8_t*)((const char*)Vts + rowv * 128 + (((kc * 4 + lg) ^ (rowv & 7)) << 4));
                oacc[dt] = mfma16(pa[kc], bv, oacc[dt]);
            }
        }
    }

    float inv[4];
#pragma unroll
    for (int r = 0; r < 4; r++) inv[r] = __builtin_amdgcn_rcpf(lrow[r]);
#pragma unroll
    for (int dt = 0; dt < 4; dt++) {
#pragma unroll
        for (int r = 0; r < 4; r++) {
            const float v = oacc[dt][r] * inv[r];
            const int q = qt * 64 + w * 16 + lg * 4 + r;
            const int d = dt * 16 + l15;
            ctx[(((size_t)(b * LQ_ + q)) * H_ + h) * DH_ + d] = (bf16_t)v;
        }
    }
}

// ---------------------------------------------------------------------------
// out = LayerNorm(X + Y0 + Y1) * g + b ; optional bf16 copy.  One block per row.
// ---------------------------------------------------------------------------
__global__ __launch_bounds__(256)
void add_ln3_kernel(const float* __restrict__ X, const float* __restrict__ Y0,
                    const float* __restrict__ Y1,
                    const float* __restrict__ g, const float* __restrict__ be,
                    float* __restrict__ of, bf16_t* __restrict__ ob) {
    const int row = blockIdx.x, t = threadIdx.x;
    const float4 xv = ((const float4*)(X + (size_t)row * 1024))[t];
    const float4 y0 = ((const float4*)(Y0 + (size_t)row * 1024))[t];
    const float4 y1 = ((const float4*)(Y1 + (size_t)row * 1024))[t];
    float v[4] = {xv.x + y0.x + y1.x, xv.y + y0.y + y1.y,
                  xv.z + y0.z + y1.z, xv.w + y0.w + y1.w};
    float s = v[0] + v[1] + v[2] + v[3];
    float s2 = v[0] * v[0] + v[1] * v[1] + v[2] * v[2] + v[3] * v[3];
#pragma unroll
    for (int m = 32; m >= 1; m >>= 1) { s += __shfl_xor(s, m); s2 += __shfl_xor(s2, m); }
    __shared__ float red[8];
    const int w = t >> 6, lane = t & 63;
    if (lane == 0) { red[w] = s; red[4 + w] = s2; }
    __syncthreads();
    s = red[0] + red[1] + red[2] + red[3];
    s2 = red[4] + red[5] + red[6] + red[7];
    const float mu = s * (1.f / 1024.f);
    const float var = s2 * (1.f / 1024.f) - mu * mu;
    const float rstd = rsqrtf(var + 1e-6f);
    const float4 gv = ((const float4*)g)[t];
    const float4 bv = ((const float4*)be)[t];
    float o[4];
    o[0] = (v[0] - mu) * rstd * gv.x + bv.x;
    o[1] = (v[1] - mu) * rstd * gv.y + bv.y;
    o[2] = (v[2] - mu) * rstd * gv.z + bv.z;
    o[3] = (v[3] - mu) * rstd * gv.w + bv.w;
    ((float4*)(of + (size_t)row * 1024))[t] = make_float4(o[0], o[1], o[2], o[3]);
    if (ob) {
        bf16x4_t qo;
        qo[0] = (bf16_t)o[0]; qo[1] = (bf16_t)o[1]; qo[2] = (bf16_t)o[2]; qo[3] = (bf16_t)o[3];
        ((bf16x4_t*)(ob + (size_t)row * 1024))[t] = qo;
    }
}

// ---------------------------------------------------------------------------
extern "C" void kernel_launch(void* const* d_in, const int* in_sizes, int n_in,
                              void* d_out, int out_size, void* d_ws, size_t ws_size,
                              hipStream_t stream) {
    (void)in_sizes; (void)n_in; (void)out_size; (void)ws_size;
    const float* q    = (const float*)d_in[0];
    const float* kv   = (const float*)d_in[1];
    const float* amap = (const float*)d_in[2];
    const float* Wq = (const float*)d_in[3];  const float* bQ = (const float*)d_in[4];
    const float* Wk = (const float*)d_in[5];  const float* bK = (const float*)d_in[6];
    const float* Wv = (const float*)d_in[7];  const float* bV = (const float*)d_in[8];
    const float* Wm = (const float*)d_in[9];  const float* bM = (const float*)d_in[10];
    const float* Wc1 = (const float*)d_in[11]; const float* bc1 = (const float*)d_in[12];
    const float* Wc2 = (const float*)d_in[13]; const float* bc2 = (const float*)d_in[14];
    const float* Wf1 = (const float*)d_in[15]; const float* bf1 = (const float*)d_in[16];
    const float* Wf2 = (const float*)d_in[17]; const float* bf2 = (const float*)d_in[18];
    const float* g1 = (const float*)d_in[19]; const float* b1 = (const float*)d_in[20];
    const float* g2 = (const float*)d_in[21]; const float* b2 = (const float*)d_in[22];

    char* w = (char*)d_ws;
    // region [0, 67108864): biasb; later p0/p1; later hb + f0/f1
    bf16_t* biasb = (bf16_t*)(w);
    float*  p0    = (float*)(w);                    // 16 MB (after attn)
    float*  p1    = (float*)(w + 16777216);         // 16 MB
    bf16_t* hb    = (bf16_t*)(w);                   // 32 MB (after add_ln3 #1)
    float*  f0    = (float*)(w + 33554432);         // 16 MB
    float*  f1    = (float*)(w + 50331648);         // 16 MB
    bf16_t* qb   = (bf16_t*)(w + 67108864);         // 8 MB ; ctx after QKV
    bf16_t* kvb  = (bf16_t*)(w + 75497472);         // 8 MB
    bf16_t* Qp   = (bf16_t*)(w + 83886080);         // 8 MB each, Q|K|V contiguous
    bf16_t* Kp   = (bf16_t*)(w + 92274688);
    bf16_t* Vp   = (bf16_t*)(w + 100663296);
    bf16_t* Wqkvb = (bf16_t*)(w + 109051904);       // 6 MB (Wq|Wk|Wv bf16)
    bf16_t* Wmb  = (bf16_t*)(w + 115343360);        // 2 MB (contiguous after Wqkvb)
    bf16_t* Wf1b = (bf16_t*)(w + 117440512);        // 8 MB
    bf16_t* Wf2b = (bf16_t*)(w + 125829120);        // 8 MB (contiguous after Wf1b)
    float*  bqkv = (float*)(w + 134217728);         // 12 KB
    bf16_t* ctx = qb;                               // qb dead after QKV gemm
    float*  xf  = (float*)Qp;                       // 16 MB over Qp+Kp (dead after attn)
    bf16_t* xb  = Vp;                               // Vp dead after attn
    (void)Wmb; (void)Wf2b; (void)kvb;

    dim3 blk(256);
    // fused f32->bf16 conversion (qb|kvb, Wqkvb|Wmb, Wf1b|Wf2b are contiguous)
    cvt_all_kernel<<<20480, blk, 0, stream>>>(q, kv, Wq, Wk, Wv, Wm, Wf1, Wf2,
                                              qb, Wqkvb, Wf1b);
    pack3_kernel<<<4, blk, 0, stream>>>(bQ, bK, bV, bqkv);

    bias_mlp_mfma<<<8192, blk, 0, stream>>>(amap, Wc1, bc1, Wc2, bc2, biasb);

    // fused QKV projection: N=3072, A chosen per column block (q for cols<1024)
    gemm_bt<3, false><<<768, blk, 0, stream>>>(qb, kvb, Wqkvb, bqkv, nullptr, Qp,
                                               4096, 3072, 1024, 1024);

    attn_kernel<<<1024, blk, 0, stream>>>(Qp, Kp, Vp, biasb, ctx);

    // out-proj, split-K=2 -> p0,p1 (overwrites biasb region, dead now)
    gemm_bt<0, true><<<dim3(256, 2), blk, 0, stream>>>(ctx, nullptr, Wmb, bM, p0, nullptr,
                                                       4096, 1024, 512, 1024);
    add_ln3_kernel<<<4096, blk, 0, stream>>>(q, p0, p1, g1, b1, xf, xb);

    // FFN1 (relu, bf16) -> hb
    gemm_bt<2, false><<<1024, blk, 0, stream>>>(xb, nullptr, Wf1b, bf1, nullptr, hb,
                                                4096, 4096, 1024, 1024);
    // FFN2, split-K=2 -> f0,f1
    gemm_bt<0, true><<<dim3(256, 2), blk, 0, stream>>>(hb, nullptr, Wf2b, bf2, f0, nullptr,
                                                       4096, 1024, 2048, 4096);
    add_ln3_kernel<<<4096, blk, 0, stream>>>(xf, f0, f1, g2, b2, (float*)d_out, nullptr);
}

// Round 8
// 329.933 us; speedup vs baseline: 1.5940x; 1.0087x over previous
//
#include <hip/hip_runtime.h>
#include <hip/hip_bf16.h>

typedef __bf16 bf16_t;
typedef __bf16 bf16x4_t __attribute__((ext_vector_type(4)));
typedef __bf16 bf16x8_t __attribute__((ext_vector_type(8)));
typedef float  f32x4_t  __attribute__((ext_vector_type(4)));

#define B_   8
#define LQ_  512
#define LKV_ 512
#define D_   1024
#define H_   16
#define DH_  64
#define FF_  4096

__device__ __forceinline__ f32x4_t mfma16(bf16x8_t a, bf16x8_t b, f32x4_t c) {
    return __builtin_amdgcn_mfma_f32_16x16x32_bf16(a, b, c, 0, 0, 0);
}

__device__ __forceinline__ void gload_lds16(const bf16_t* g, bf16_t* l) {
    __builtin_amdgcn_global_load_lds(
        (const __attribute__((address_space(1))) void*)g,
        (__attribute__((address_space(3))) void*)l, 16, 0, 0);
}

// bijective XCD chunking: blocks with pid%8==x (same XCD, HW round-robin)
// get a CONTIGUOUS range of work indices.  Requires nwg % 8 == 0.
__device__ __forceinline__ int xcd_swz(int pid, int nwg) {
    return (pid & 7) * (nwg >> 3) + (pid >> 3);
}

// fast GELU: h * sigmoid(1.702 h).
__device__ __forceinline__ float gelu_fast(float h) {
    const float e = exp2f(h * -2.45546696f);     // exp(-1.702 h)
    return h * __builtin_amdgcn_rcpf(1.f + e);
}

// ---------------------------------------------------------------------------
// fused f32 -> bf16 convert for all 8 tensors (one launch).
// ---------------------------------------------------------------------------
__global__ __launch_bounds__(256)
void cvt_all_kernel(const float* __restrict__ q,  const float* __restrict__ kv,
                    const float* __restrict__ Wq, const float* __restrict__ Wk,
                    const float* __restrict__ Wv, const float* __restrict__ Wm,
                    const float* __restrict__ Wf1,const float* __restrict__ Wf2,
                    bf16_t* __restrict__ dq, bf16_t* __restrict__ dW,
                    bf16_t* __restrict__ dF) {
    const int i = blockIdx.x * 256 + threadIdx.x;    // grid 20480 -> i < 5242880
    const float* s; bf16_t* d; int j;
    if (i < 1048576)      { s = q;   d = dq;           j = i; }
    else if (i < 2097152) { s = kv;  d = dq + 4194304; j = i - 1048576; }
    else if (i < 2359296) { s = Wq;  d = dW;           j = i - 2097152; }
    else if (i < 2621440) { s = Wk;  d = dW + 1048576; j = i - 2359296; }
    else if (i < 2883584) { s = Wv;  d = dW + 2097152; j = i - 2621440; }
    else if (i < 3145728) { s = Wm;  d = dW + 3145728; j = i - 2883584; }
    else if (i < 4194304) { s = Wf1; d = dF;           j = i - 3145728; }
    else                  { s = Wf2; d = dF + 4194304; j = i - 4194304; }
    const float4 v = ((const float4*)s)[j];
    bf16x4_t o;
    o[0] = (bf16_t)v.x; o[1] = (bf16_t)v.y; o[2] = (bf16_t)v.z; o[3] = (bf16_t)v.w;
    ((bf16x4_t*)d)[j] = o;
}

__global__ __launch_bounds__(256)
void pack3_kernel(const float* __restrict__ a, const float* __restrict__ b,
                  const float* __restrict__ c, float* __restrict__ o) {
    const int i = blockIdx.x * 256 + threadIdx.x;   // grid 4 -> i < 1024
    o[i] = a[i]; o[1024 + i] = b[i]; o[2048 + i] = c[i];
}

// ---------------------------------------------------------------------------
// AttentionBiasMLP via MFMA.  One wave handles 64 consecutive positions.
// ---------------------------------------------------------------------------
__global__ __launch_bounds__(256)
void bias_mlp_mfma(const float* __restrict__ amap,
                   const float* __restrict__ Wc1, const float* __restrict__ bc1,
                   const float* __restrict__ Wc2, const float* __restrict__ bc2,
                   bf16_t* __restrict__ biasb) {
    __shared__ __align__(16) char lds[4][8192];  // per wave: Xs [0,3072) rows 48B; Hs [3072,8192) rows 80B
    const int t = threadIdx.x, lane = t & 63, w = t >> 6;
    const int l15 = lane & 15, lg = lane >> 4;
    char* Xs = lds[w];
    char* Hs = lds[w] + 3072;

    // --- weight fragments (registers, once).  W1 *= ln2 (log2 input fold) ---
    bf16x8_t b1f[2], b2f;
    f32x4_t bc1v[2];
#pragma unroll
    for (int ot = 0; ot < 2; ot++) {
        bf16x8_t v;
#pragma unroll
        for (int i = 0; i < 8; i++) {
            const int kk = (lg * 8 + i) & 15;                       // in-bounds always
            const float wv = Wc1[(ot * 16 + l15) * 16 + kk] * 0.69314718055994531f;
            v[i] = (lg < 2) ? (bf16_t)wv : (bf16_t)0.f;             // zero-pad K 16->32
        }
        b1f[ot] = v;
        const float bb = bc1[ot * 16 + l15];
        bc1v[ot] = f32x4_t{bb, bb, bb, bb};
    }
    {
        bf16x8_t v;
#pragma unroll
        for (int i = 0; i < 8; i++) v[i] = (bf16_t)Wc2[l15 * 32 + lg * 8 + i];
        b2f = v;
    }
    const float bc2s = bc2[l15];
    const f32x4_t cinit2 = f32x4_t{bc2s, bc2s, bc2s, bc2s};

    // --- positions ---
    const int posb = (blockIdx.x * 4 + w) * 64;
    const int b  = posb >> 18;
    const int q  = (posb >> 9) & 511;
    const int k0 = posb & 511;

    // --- load 16 channels, log2, stage to LDS (row = lane, 16 bf16, stride 48B) ---
    const float* src = amap + (size_t)(b * 16) * 263169 + (size_t)(q + 1) * 513 + (k0 + 1 + lane);
    bf16_t xr[16];
#pragma unroll
    for (int c = 0; c < 16; c++) {
        const float v = src[(size_t)c * 263169];
        xr[c] = (bf16_t)__log2f(v + 1e-6f);
    }
    *(bf16x8_t*)(Xs + lane * 48)      = *(bf16x8_t*)&xr[0];
    *(bf16x8_t*)(Xs + lane * 48 + 16) = *(bf16x8_t*)&xr[8];

    // --- layer 1 MFMA: A-frag row=l15 (pos); lg>=2 lanes re-read valid bytes, B=0 there ---
    const int lgm16 = (lg & 1) * 16;
    f32x4_t h1[4][2];
#pragma unroll
    for (int p = 0; p < 4; p++) {
        const bf16x8_t a1 = *(const bf16x8_t*)(Xs + (p * 16 + l15) * 48 + lgm16);
#pragma unroll
        for (int ot = 0; ot < 2; ot++)
            h1[p][ot] = mfma16(a1, b1f[ot], bc1v[ot]);
    }

    // --- GELU (sigmoid form), write H to LDS [64][40bf16] ---
#pragma unroll
    for (int p = 0; p < 4; p++)
#pragma unroll
        for (int ot = 0; ot < 2; ot++)
#pragma unroll
            for (int r = 0; r < 4; r++) {
                const float g = gelu_fast(h1[p][ot][r]);
                *(bf16_t*)(Hs + (p * 16 + lg * 4 + r) * 80 + (ot * 16 + l15) * 2) = (bf16_t)g;
            }

    // --- layer 2 MFMA + direct bf16x4 store (C rows are 4 consecutive k) ---
    const size_t obase = ((size_t)(b * 16 + l15) * 512 + q) * 512 + k0;
#pragma unroll
    for (int p = 0; p < 4; p++) {
        const bf16x8_t a2 = *(const bf16x8_t*)(Hs + (p * 16 + l15) * 80 + lg * 16);
        const f32x4_t o2 = mfma16(a2, b2f, cinit2);
        bf16x4_t ov;
#pragma unroll
        for (int r = 0; r < 4; r++) ov[r] = (bf16_t)o2[r];
        *(bf16x4_t*)&biasb[obase + p * 16 + lg * 4] = ov;
    }
}

// ---------------------------------------------------------------------------
// bf16 GEMM: C[M,N] = A[M,K] @ W[N,K]^T + bias.  128x128 tile, BK=32,
// 3-slot counted-vmcnt pipeline (T4): 2 tiles prefetched ahead, vmcnt(4)
// waits only the OLDEST tile's loads, ONE barrier per K-step, no mid-loop
// drain.  Slot written at iter kt is (kt+2)%3, last read at iter kt-1 and
// protected by this iter's barrier.  4 waves 2x2, 16x16x32 MFMA.
// EPI: 0 = bf16 SPLIT partial out, 1 = bf16 out, 2 = relu bf16, 3 = QKV fused
// ---------------------------------------------------------------------------
template <int EPI, bool SPLIT>
__global__ __launch_bounds__(256)
void gemm_bt(const bf16_t* __restrict__ A, const bf16_t* __restrict__ A2,
             const bf16_t* __restrict__ Bw,
             const float* __restrict__ bias,
             bf16_t* __restrict__ Cb, int M, int N, int Klen, int lda) {
    __shared__ __align__(16) bf16_t As[3][128 * 32];
    __shared__ __align__(16) bf16_t Bs[3][128 * 32];
    const int t = threadIdx.x, lane = t & 63, w = t >> 6;
    const int wr = w >> 1, wc = w & 1;
    const int ntn = N >> 7;
    const int nwg = (M >> 7) * ntn;
    const int wg  = xcd_swz((int)blockIdx.x, nwg);
    const int gsz = 8 * ntn;                 // GM=8 supertile
    const int gid = wg / gsz;
    const int rem = wg - gid * gsz;
    const int tm  = gid * 8 + (rem & 7);
    const int tn  = rem >> 3;
    const int l15 = lane & 15, lg = lane >> 4;
    const int ks = SPLIT ? blockIdx.y : 0;
    const int koff = SPLIT ? ks * Klen : 0;
    if (EPI == 3 && tn >= 8) A = A2;   // Q cols use q-input; K/V cols use kv-input

    // per-thread staging coordinates
    const int r0 = t >> 2,          k0 = t & 3;
    const int r1 = (t + 256) >> 2,  k1 = t & 3;
    const int b0 = (w * 64) * 8;
    const int b1 = (256 + w * 64) * 8;
    const bf16_t* Abase0 = A  + (size_t)(tm * 128 + r0) * lda + koff + k0 * 8;
    const bf16_t* Abase1 = A  + (size_t)(tm * 128 + r1) * lda + koff + k1 * 8;
    const bf16_t* Bbase0 = Bw + (size_t)(tn * 128 + r0) * lda + koff + k0 * 8;
    const bf16_t* Bbase1 = Bw + (size_t)(tn * 128 + r1) * lda + koff + k1 * 8;

    f32x4_t acc[4][4];
#pragma unroll
    for (int i = 0; i < 4; i++)
#pragma unroll
        for (int j = 0; j < 4; j++) acc[i][j] = f32x4_t{0.f, 0.f, 0.f, 0.f};

    const int nk = Klen >> 5;   // >= 16 for all our shapes

#define STAGE(KT, S)                                    \
    do {                                                \
        const int _ko = (KT) * 32;                      \
        gload_lds16(Abase0 + _ko, &As[(S)][b0]);        \
        gload_lds16(Abase1 + _ko, &As[(S)][b1]);        \
        gload_lds16(Bbase0 + _ko, &Bs[(S)][b0]);        \
        gload_lds16(Bbase1 + _ko, &Bs[(S)][b1]);        \
    } while (0)

    STAGE(0, 0);
    STAGE(1, 1);

    int cur = 0;                 // slot of tile kt
    for (int kt = 0; kt < nk; ++kt) {
        if (kt + 1 < nk) { asm volatile("s_waitcnt vmcnt(4)" ::: "memory"); }
        else             { asm volatile("s_waitcnt vmcnt(0)" ::: "memory"); }
        __syncthreads();
        // prefetch tile kt+2 into slot (cur+2)%3 (its readers finished pre-barrier)
        if (kt + 2 < nk) {
            const int s2 = cur >= 1 ? cur - 1 : cur + 2;   // (cur+2)%3
            STAGE(kt + 2, s2);
        }

        const bf16_t* Ac = As[cur];
        const bf16_t* Bc = Bs[cur];
        bf16x8_t af[4], bfv[4];
#pragma unroll
        for (int mt = 0; mt < 4; mt++)
            af[mt] = *(const bf16x8_t*)&Ac[(wr * 64 + mt * 16 + l15) * 32 + lg * 8];
#pragma unroll
        for (int nt = 0; nt < 4; nt++)
            bfv[nt] = *(const bf16x8_t*)&Bc[(wc * 64 + nt * 16 + l15) * 32 + lg * 8];
#pragma unroll
        for (int mt = 0; mt < 4; mt++)
#pragma unroll
            for (int nt = 0; nt < 4; nt++)
                acc[mt][nt] = mfma16(af[mt], bfv[nt], acc[mt][nt]);

        cur = cur < 2 ? cur + 1 : 0;
    }
#undef STAGE

#pragma unroll
    for (int nt = 0; nt < 4; nt++) {
        const int col = tn * 128 + wc * 64 + nt * 16 + l15;
        float bv = bias[col];
        if (SPLIT && ks != 0) bv = 0.f;
#pragma unroll
        for (int mt = 0; mt < 4; mt++) {
#pragma unroll
            for (int r = 0; r < 4; r++) {
                const int row = tm * 128 + wr * 64 + mt * 16 + lg * 4 + r;
                float v = acc[mt][nt][r] + bv;
                if (EPI == 2) v = fmaxf(v, 0.f);
                if (EPI == 3 && tn < 8) v *= 0.125f;     // fold 1/sqrt(DH) into Q
                if (SPLIT)
                    Cb[(size_t)ks * M * N + (size_t)row * N + col] = (bf16_t)v;
                else if (EPI == 3)
                    Cb[(size_t)(col >> 10) * 4194304 + (size_t)row * 1024 + (col & 1023)] = (bf16_t)v;
                else Cb[(size_t)row * N + col] = (bf16_t)v;
            }
        }
    }
}

// ---------------------------------------------------------------------------
// Flash attention with additive bias.  One block = (b, h, 64-row q-tile).
// Q fragments hoisted out of the KV loop.
// ---------------------------------------------------------------------------
__global__ __launch_bounds__(256)
void attn_kernel(const bf16_t* __restrict__ Qp, const bf16_t* __restrict__ Kp,
                 const bf16_t* __restrict__ Vp, const bf16_t* __restrict__ biasb,
                 bf16_t* __restrict__ ctx) {
    __shared__ __align__(16) bf16_t Qs[64 * 64];
    __shared__ __align__(16) bf16_t Ks[64 * 64];
    __shared__ __align__(16) bf16_t Vts[64 * 64];   // V transposed: Vts[d][k]
    __shared__ __align__(16) bf16_t Ps[64 * 64];
    __shared__ __align__(16) bf16_t Bbs[64 * 64];   // bias tile, linear [q][k]

    const int bid = xcd_swz((int)blockIdx.x, 1024);
    const int qt = bid & 7, h = (bid >> 3) & 15, b = bid >> 7;
    const int t = threadIdx.x, lane = t & 63, w = t >> 6;
    const int l15 = lane & 15, lg = lane >> 4;

    // stage Q tile (swizzled)
#pragma unroll
    for (int i = 0; i < 2; i++) {
        const int c = t + i * 256;
        const int row = c >> 3, cg = c & 7;
        const uint4 v = *(const uint4*)&Qp[(((size_t)(b * LQ_ + qt * 64 + row)) * H_ + h) * DH_ + cg * 8];
        *(uint4*)((char*)Qs + row * 128 + ((cg ^ (row & 7)) << 4)) = v;
    }
    __syncthreads();

    // hoist Q fragments (loop-invariant)
    bf16x8_t aq[2];
    {
        const int rowq = w * 16 + l15;
#pragma unroll
        for (int kc = 0; kc < 2; kc++)
            aq[kc] = *(const bf16x8_t*)((const char*)Qs + rowq * 128 + (((kc * 4 + lg) ^ (rowq & 7)) << 4));
    }

    f32x4_t oacc[4];
#pragma unroll
    for (int i = 0; i < 4; i++) oacc[i] = f32x4_t{0.f, 0.f, 0.f, 0.f};
    float mrow[4] = {-1e30f, -1e30f, -1e30f, -1e30f};
    float lrow[4] = {0.f, 0.f, 0.f, 0.f};

    const bf16_t* bias_tile = biasb + ((size_t)(b * H_ + h) * LQ_ + qt * 64) * LKV_;

    for (int kt = 0; kt < 8; ++kt) {
        __syncthreads();   // previous iteration done with Ks/Vts/Bbs
#pragma unroll
        for (int i = 0; i < 2; i++) {
            const int c = t + i * 256;
            const int row = c >> 3, cg = c & 7;
            const uint4 v = *(const uint4*)&Kp[(((size_t)(b * LKV_ + kt * 64 + row)) * H_ + h) * DH_ + cg * 8];
            *(uint4*)((char*)Ks + row * 128 + ((cg ^ (row & 7)) << 4)) = v;
        }
        // stage bias tile via registers (coalesced 16B, linear LDS [q][k])
#pragma unroll
        for (int i = 0; i < 2; i++) {
            const int c = t + i * 256;
            const int row = c >> 3, cg = c & 7;
            const uint4 bv4 = *(const uint4*)&bias_tile[(size_t)row * LKV_ + kt * 64 + cg * 8];
            *(uint4*)&Bbs[row * 64 + cg * 8] = bv4;
        }
#pragma unroll
        for (int i = 0; i < 2; i++) {
            const int c = t + i * 256;
            const int k = c >> 3, dg = c & 7;
            const bf16x8_t vv = *(const bf16x8_t*)&Vp[(((size_t)(b * LKV_ + kt * 64 + k)) * H_ + h) * DH_ + dg * 8];
#pragma unroll
            for (int j = 0; j < 8; j++) {
                const int d = dg * 8 + j;
                *(bf16_t*)((char*)Vts + d * 128 + ((((k * 2) >> 4) ^ (d & 7)) << 4) + ((k * 2) & 15)) = vv[j];
            }
        }
        __syncthreads();

        // S = Q K^T
        f32x4_t sacc[4];
#pragma unroll
        for (int i = 0; i < 4; i++) sacc[i] = f32x4_t{0.f, 0.f, 0.f, 0.f};
#pragma unroll
        for (int nt = 0; nt < 4; nt++) {
            const int rowk = nt * 16 + l15;
#pragma unroll
            for (int kc = 0; kc < 2; kc++) {
                const bf16x8_t bk = *(const bf16x8_t*)((const char*)Ks + rowk * 128 + (((kc * 4 + lg) ^ (rowk & 7)) << 4));
                sacc[nt] = mfma16(aq[kc], bk, sacc[nt]);
            }
        }

        // bias add + online softmax.  D-layout: row = 4*lg + r, col = 16*nt + l15
        float esc[4];
#pragma unroll
        for (int r = 0; r < 4; r++) {
            const int qr = w * 16 + lg * 4 + r;
            float mx = -1e30f;
#pragma unroll
            for (int nt = 0; nt < 4; nt++) {
                const float bvv = (float)Bbs[qr * 64 + nt * 16 + l15];
                const float v = sacc[nt][r] + bvv;
                sacc[nt][r] = v;
                mx = fmaxf(mx, v);
            }
#pragma unroll
            for (int msk = 8; msk >= 1; msk >>= 1) mx = fmaxf(mx, __shfl_xor(mx, msk));
            const float mnew = fmaxf(mrow[r], mx);
            esc[r] = __expf(mrow[r] - mnew);
            mrow[r] = mnew;
            float rs = 0.f;
#pragma unroll
            for (int nt = 0; nt < 4; nt++) {
                const float p = __expf(sacc[nt][r] - mnew);
                sacc[nt][r] = p;
                rs += p;
            }
#pragma unroll
            for (int msk = 8; msk >= 1; msk >>= 1) rs += __shfl_xor(rs, msk);
            lrow[r] = lrow[r] * esc[r] + rs;
        }

        // write P (bf16) into own wave strip of Ps
#pragma unroll
        for (int r = 0; r < 4; r++) {
            const int prow = w * 16 + lg * 4 + r;
#pragma unroll
            for (int nt = 0; nt < 4; nt++) {
                const int pc2 = (nt * 16 + l15) * 2;
                *(bf16_t*)((char*)Ps + prow * 128 + (((pc2 >> 4) ^ (prow & 7)) << 4) + (pc2 & 15)) =
                    (bf16_t)sacc[nt][r];
            }
        }
        asm volatile("s_waitcnt lgkmcnt(0)" ::: "memory");
        __builtin_amdgcn_sched_barrier(0);

        // rescale O then accumulate P @ V
#pragma unroll
        for (int dt = 0; dt < 4; dt++)
#pragma unroll
            for (int r = 0; r < 4; r++) oacc[dt][r] *= esc[r];

        bf16x8_t pa[2];
        {
            const int rowp = w * 16 + l15;
#pragma unroll
            for (int kc = 0; kc < 2; kc++)
                pa[kc] = *(const bf16x8_t*)((const char*)Ps + rowp * 128 + (((kc * 4 + lg) ^ (rowp & 7)) << 4));
        }
#pragma unroll
        for (int dt = 0; dt < 4; dt++) {
            const int rowv = dt * 16 + l15;
#pragma unroll
            for (int kc = 0; kc < 2; kc++) {
                const bf16x8_t bv = *(const bf16x8_t*)((const char*)Vts + rowv * 128 + (((kc * 4 + lg) ^ (rowv & 7)) << 4));
                oacc[dt] = mfma16(pa[kc], bv, oacc[dt]);
            }
        }
    }

    float inv[4];
#pragma unroll
    for (int r = 0; r < 4; r++) inv[r] = __builtin_amdgcn_rcpf(lrow[r]);
#pragma unroll
    for (int dt = 0; dt < 4; dt++) {
#pragma unroll
        for (int r = 0; r < 4; r++) {
            const float v = oacc[dt][r] * inv[r];
            const int q = qt * 64 + w * 16 + lg * 4 + r;
            const int d = dt * 16 + l15;
            ctx[(((size_t)(b * LQ_ + q)) * H_ + h) * DH_ + d] = (bf16_t)v;
        }
    }
}

// ---------------------------------------------------------------------------
// out = LayerNorm(X + Y0 + Y1) * g + b ; Y0/Y1 are bf16 split-K partials.
// ---------------------------------------------------------------------------
__global__ __launch_bounds__(256)
void add_ln3_kernel(const float* __restrict__ X, const bf16_t* __restrict__ Y0,
                    const bf16_t* __restrict__ Y1,
                    const float* __restrict__ g, const float* __restrict__ be,
                    float* __restrict__ of, bf16_t* __restrict__ ob) {
    const int row = blockIdx.x, t = threadIdx.x;
    const float4 xv = ((const float4*)(X + (size_t)row * 1024))[t];
    const bf16x4_t y0 = ((const bf16x4_t*)(Y0 + (size_t)row * 1024))[t];
    const bf16x4_t y1 = ((const bf16x4_t*)(Y1 + (size_t)row * 1024))[t];
    float v[4] = {xv.x + (float)y0[0] + (float)y1[0], xv.y + (float)y0[1] + (float)y1[1],
                  xv.z + (float)y0[2] + (float)y1[2], xv.w + (float)y0[3] + (float)y1[3]};
    float s = v[0] + v[1] + v[2] + v[3];
    float s2 = v[0] * v[0] + v[1] * v[1] + v[2] * v[2] + v[3] * v[3];
#pragma unroll
    for (int m = 32; m >= 1; m >>= 1) { s += __shfl_xor(s, m); s2 += __shfl_xor(s2, m); }
    __shared__ float red[8];
    const int w = t >> 6, lane = t & 63;
    if (lane == 0) { red[w] = s; red[4 + w] = s2; }
    __syncthreads();
    s = red[0] + red[1] + red[2] + red[3];
    s2 = red[4] + red[5] + red[6] + red[7];
    const float mu = s * (1.f / 1024.f);
    const float var = s2 * (1.f / 1024.f) - mu * mu;
    const float rstd = rsqrtf(var + 1e-6f);
    const float4 gv = ((const float4*)g)[t];
    const float4 bv = ((const float4*)be)[t];
    float o[4];
    o[0] = (v[0] - mu) * rstd * gv.x + bv.x;
    o[1] = (v[1] - mu) * rstd * gv.y + bv.y;
    o[2] = (v[2] - mu) * rstd * gv.z + bv.z;
    o[3] = (v[3] - mu) * rstd * gv.w + bv.w;
    ((float4*)(of + (size_t)row * 1024))[t] = make_float4(o[0], o[1], o[2], o[3]);
    if (ob) {
        bf16x4_t qo;
        qo[0] = (bf16_t)o[0]; qo[1] = (bf16_t)o[1]; qo[2] = (bf16_t)o[2]; qo[3] = (bf16_t)o[3];
        ((bf16x4_t*)(ob + (size_t)row * 1024))[t] = qo;
    }
}

// ---------------------------------------------------------------------------
extern "C" void kernel_launch(void* const* d_in, const int* in_sizes, int n_in,
                              void* d_out, int out_size, void* d_ws, size_t ws_size,
                              hipStream_t stream) {
    (void)in_sizes; (void)n_in; (void)out_size; (void)ws_size;
    const float* q    = (const float*)d_in[0];
    const float* kv   = (const float*)d_in[1];
    const float* amap = (const float*)d_in[2];
    const float* Wq = (const float*)d_in[3];  const float* bQ = (const float*)d_in[4];
    const float* Wk = (const float*)d_in[5];  const float* bK = (const float*)d_in[6];
    const float* Wv = (const float*)d_in[7];  const float* bV = (const float*)d_in[8];
    const float* Wm = (const float*)d_in[9];  const float* bM = (const float*)d_in[10];
    const float* Wc1 = (const float*)d_in[11]; const float* bc1 = (const float*)d_in[12];
    const float* Wc2 = (const float*)d_in[13]; const float* bc2 = (const float*)d_in[14];
    const float* Wf1 = (const float*)d_in[15]; const float* bf1 = (const float*)d_in[16];
    const float* Wf2 = (const float*)d_in[17]; const float* bf2 = (const float*)d_in[18];
    const float* g1 = (const float*)d_in[19]; const float* b1 = (const float*)d_in[20];
    const float* g2 = (const float*)d_in[21]; const float* b2 = (const float*)d_in[22];

    char* w = (char*)d_ws;
    bf16_t* biasb = (bf16_t*)(w);                   // 64 MB, dead after attn
    bf16_t* p0    = (bf16_t*)(w);                   // 8 MB partial (after attn)
    bf16_t* p1    = (bf16_t*)(w + 8388608);         // 8 MB partial
    bf16_t* hb    = (bf16_t*)(w);                   // 32 MB (after add_ln3 #1)
    bf16_t* f0    = (bf16_t*)(w + 33554432);        // 8 MB partial
    bf16_t* f1    = (bf16_t*)(w + 41943040);        // 8 MB partial
    bf16_t* qb   = (bf16_t*)(w + 67108864);         // 8 MB ; ctx after QKV
    bf16_t* kvb  = (bf16_t*)(w + 75497472);         // 8 MB
    bf16_t* Qp   = (bf16_t*)(w + 83886080);         // 8 MB each, Q|K|V contiguous
    bf16_t* Kp   = (bf16_t*)(w + 92274688);
    bf16_t* Vp   = (bf16_t*)(w + 100663296);
    bf16_t* Wqkvb = (bf16_t*)(w + 109051904);       // 6 MB (Wq|Wk|Wv bf16)
    bf16_t* Wmb  = (bf16_t*)(w + 115343360);        // 2 MB (contiguous after Wqkvb)
    bf16_t* Wf1b = (bf16_t*)(w + 117440512);        // 8 MB
    bf16_t* Wf2b = (bf16_t*)(w + 125829120);        // 8 MB (contiguous after Wf1b)
    float*  bqkv = (float*)(w + 134217728);         // 12 KB
    bf16_t* ctx = qb;                               // qb dead after QKV gemm
    float*  xf  = (float*)Qp;                       // 16 MB over Qp+Kp (dead after attn)
    bf16_t* xb  = Vp;                               // Vp dead after attn

    dim3 blk(256);
    cvt_all_kernel<<<20480, blk, 0, stream>>>(q, kv, Wq, Wk, Wv, Wm, Wf1, Wf2,
                                              qb, Wqkvb, Wf1b);
    pack3_kernel<<<4, blk, 0, stream>>>(bQ, bK, bV, bqkv);

    bias_mlp_mfma<<<8192, blk, 0, stream>>>(amap, Wc1, bc1, Wc2, bc2, biasb);

    // fused QKV projection: N=3072, A chosen per column block (q for cols<1024)
    gemm_bt<3, false><<<768, blk, 0, stream>>>(qb, kvb, Wqkvb, bqkv, Qp,
                                               4096, 3072, 1024, 1024);

    attn_kernel<<<1024, blk, 0, stream>>>(Qp, Kp, Vp, biasb, ctx);

    // out-proj, split-K=2 -> bf16 partials p0,p1 (biasb region, dead now)
    gemm_bt<0, true><<<dim3(256, 2), blk, 0, stream>>>(ctx, nullptr, Wmb, bM, p0,
                                                       4096, 1024, 512, 1024);
    add_ln3_kernel<<<4096, blk, 0, stream>>>(q, p0, p1, g1, b1, xf, xb);

    // FFN1 (relu, bf16) -> hb
    gemm_bt<2, false><<<1024, blk, 0, stream>>>(xb, nullptr, Wf1b, bf1, hb,
                                                4096, 4096, 1024, 1024);
    // FFN2, split-K=2 -> bf16 partials f0,f1
    gemm_bt<0, true><<<dim3(256, 2), blk, 0, stream>>>(hb, nullptr, Wf2b, bf2, f0,
                                                       4096, 1024, 2048, 4096);
    add_ln3_kernel<<<4096, blk, 0, stream>>>(xf, f0, f1, g2, b2, (float*)d_out, nullptr);
}